// Round 1
// baseline (6688.007 us; speedup 1.0000x reference)
//
#include <hip/hip_runtime.h>
#include <hip/hip_bf16.h>
#include <math.h>

#define F_IN  128
#define HIDC  256
#define NG    8
#define EPS_BN 1e-5f

// ---------- helpers: sortable-uint encoding for float atomicMax ----------
static __device__ __forceinline__ unsigned f2sort(float f) {
    unsigned u = __float_as_uint(f);
    return (u & 0x80000000u) ? ~u : (u | 0x80000000u);
}
static __device__ __forceinline__ float sort2f(unsigned u) {
    return (u & 0x80000000u) ? __uint_as_float(u ^ 0x80000000u)
                             : __uint_as_float(~u);
}

// ---------- GEMM: C[M,Ncol] = A[M,K] @ W[K,Ncol]; K%16==0, Ncol%64==0 ----
__global__ __launch_bounds__(256)
void gemm_kernel(const float* __restrict__ A, const float* __restrict__ W,
                 float* __restrict__ C, int M, int K, int Ncol) {
    const int BM = 64, BN = 64, BK = 16;
    __shared__ float As[16][64 + 1];
    __shared__ float Ws[16][64];
    int m0 = blockIdx.y * BM;
    int n0 = blockIdx.x * BN;
    int t = threadIdx.x;
    int tx = t % 16, ty = t / 16;
    float acc[4][4] = {};
    for (int k0 = 0; k0 < K; k0 += BK) {
#pragma unroll
        for (int j = 0; j < 4; ++j) {           // A tile: 64x16
            int i = t + 256 * j;
            int r = i / 16, c = i % 16;
            int gm = m0 + r;
            As[c][r] = (gm < M) ? A[(long)gm * K + k0 + c] : 0.f;
        }
#pragma unroll
        for (int j = 0; j < 4; ++j) {           // W tile: 16x64
            int i = t + 256 * j;
            int c = i / 64, n = i % 64;
            Ws[c][n] = W[(long)(k0 + c) * Ncol + n0 + n];
        }
        __syncthreads();
#pragma unroll
        for (int c = 0; c < BK; ++c) {
            float a[4], b[4];
#pragma unroll
            for (int i = 0; i < 4; ++i) a[i] = As[c][ty * 4 + i];
#pragma unroll
            for (int j = 0; j < 4; ++j) b[j] = Ws[c][tx * 4 + j];
#pragma unroll
            for (int i = 0; i < 4; ++i)
#pragma unroll
                for (int j = 0; j < 4; ++j)
                    acc[i][j] = fmaf(a[i], b[j], acc[i][j]);
        }
        __syncthreads();
    }
#pragma unroll
    for (int i = 0; i < 4; ++i) {
        int gm = m0 + ty * 4 + i;
        if (gm >= M) continue;
#pragma unroll
        for (int j = 0; j < 4; ++j)
            C[(long)gm * Ncol + n0 + tx * 4 + j] = acc[i][j];
    }
}

// ---------- per-node attention logits: asrc[n,h] = sum_d h[n,h,d]*wsrc[h,d]
__global__ __launch_bounds__(256)
void alpha_reduce_kernel(const float* __restrict__ h,
                         const float* __restrict__ wsrc,
                         const float* __restrict__ wdst,
                         float* __restrict__ asrc, float* __restrict__ adst,
                         int N, int H) {
    int wid = threadIdx.x >> 6;
    int lane = threadIdx.x & 63;
    int n = blockIdx.x * 4 + wid;
    if (n >= N) return;
    float ps[4], pd[4];
#pragma unroll
    for (int j = 0; j < 4; ++j) {
        int c = j * 64 + lane;
        float hv = h[(long)n * HIDC + c];
        ps[j] = hv * wsrc[c];
        pd[j] = hv * wdst[c];
    }
    if (H == 1) {
        float s = ps[0] + ps[1] + ps[2] + ps[3];
        float d = pd[0] + pd[1] + pd[2] + pd[3];
        for (int o = 32; o > 0; o >>= 1) {
            s += __shfl_down(s, o, 64);
            d += __shfl_down(d, o, 64);
        }
        if (lane == 0) { asrc[n] = s; adst[n] = d; }
    } else {  // H == 4, D == 64: each j IS one head
#pragma unroll
        for (int j = 0; j < 4; ++j) {
            float s = ps[j], d = pd[j];
            for (int o = 32; o > 0; o >>= 1) {
                s += __shfl_down(s, o, 64);
                d += __shfl_down(d, o, 64);
            }
            if (lane == 0) { asrc[n * 4 + j] = s; adst[n * 4 + j] = d; }
        }
    }
}

// ---------- edge pass 1: segment max (sortable-uint atomicMax) ----------
__global__ void edge_max_kernel(const int* __restrict__ ei, int E, int N,
                                const float* __restrict__ asrc,
                                const float* __restrict__ adst,
                                unsigned* __restrict__ menc, int H) {
    int e = blockIdx.x * blockDim.x + threadIdx.x;
    int Etot = E + N;
    if (e >= Etot) return;
    int s = (e < E) ? ei[e] : (e - E);
    int d = (e < E) ? ei[E + e] : (e - E);
    for (int h = 0; h < H; ++h) {
        float v = asrc[s * H + h] + adst[d * H + h];
        v = (v >= 0.f) ? v : 0.2f * v;
        atomicMax(&menc[d * H + h], f2sort(v));
    }
}

// ---------- edge pass 2: softmax denominator ----------
__global__ void edge_denom_kernel(const int* __restrict__ ei, int E, int N,
                                  const float* __restrict__ asrc,
                                  const float* __restrict__ adst,
                                  const unsigned* __restrict__ menc,
                                  float* __restrict__ denom, int H) {
    int e = blockIdx.x * blockDim.x + threadIdx.x;
    int Etot = E + N;
    if (e >= Etot) return;
    int s = (e < E) ? ei[e] : (e - E);
    int d = (e < E) ? ei[E + e] : (e - E);
    for (int h = 0; h < H; ++h) {
        float v = asrc[s * H + h] + adst[d * H + h];
        v = (v >= 0.f) ? v : 0.2f * v;
        float m = sort2f(menc[d * H + h]);
        atomicAdd(&denom[d * H + h], expf(v - m));
    }
}

// ---------- edge pass 3: alpha-weighted message scatter (wave per edge) ----
__global__ __launch_bounds__(256)
void edge_scatter_kernel(const int* __restrict__ ei, int E, int N,
                         const float* __restrict__ asrc,
                         const float* __restrict__ adst,
                         const unsigned* __restrict__ menc,
                         const float* __restrict__ denom,
                         const float* __restrict__ h,
                         float* __restrict__ agg, int H) {
    int wid = threadIdx.x >> 6, lane = threadIdx.x & 63;
    long e = (long)blockIdx.x * 4 + wid;
    int Etot = E + N;
    if (e >= Etot) return;
    int s = (e < E) ? ei[e] : (int)(e - E);
    int d = (e < E) ? ei[E + e] : (int)(e - E);
    int D = HIDC / H;
    int head = (lane * 4) / D;
    float v = asrc[s * H + head] + adst[d * H + head];
    v = (v >= 0.f) ? v : 0.2f * v;
    float m = sort2f(menc[d * H + head]);
    float alpha = expf(v - m) / (denom[d * H + head] + 1e-16f);
    const float4* hs = (const float4*)(h + (long)s * HIDC);
    float4 hv = hs[lane];
    float* ag = agg + (long)d * HIDC + lane * 4;
    atomicAdd(ag + 0, hv.x * alpha);
    atomicAdd(ag + 1, hv.y * alpha);
    atomicAdd(ag + 2, hv.z * alpha);
    atomicAdd(ag + 3, hv.w * alpha);
}

// ---------- BatchNorm stats (per-channel sum / sumsq) ----------
__global__ __launch_bounds__(256)
void bn_stats_kernel(const float* __restrict__ h, int N,
                     float* __restrict__ sum, float* __restrict__ sumsq) {
    int c = threadIdx.x;
    int r0 = blockIdx.x * 128;
    int rend = min(r0 + 128, N);
    float s = 0.f, q = 0.f;
    for (int r = r0; r < rend; ++r) {
        float v = h[(long)r * HIDC + c];
        s += v;
        q += v * v;
    }
    atomicAdd(&sum[c], s);
    atomicAdd(&sumsq[c], q);
}

// ---------- BN apply + relu (in place); bias cancels through BN ----------
__global__ void bn_apply_relu_kernel(float* __restrict__ h, int N,
                                     const float* __restrict__ sum,
                                     const float* __restrict__ sumsq,
                                     const float* __restrict__ gamma,
                                     const float* __restrict__ beta) {
    long idx = (long)blockIdx.x * blockDim.x + threadIdx.x;
    long total = (long)N * HIDC;
    if (idx >= total) return;
    int c = (int)(idx & (HIDC - 1));
    float invN = 1.f / (float)N;
    float mu = sum[c] * invN;
    float var = sumsq[c] * invN - mu * mu;
    float inv = rsqrtf(var + EPS_BN);
    float v = gamma[c] * (h[idx] - mu) * inv + beta[c];
    h[idx] = v > 0.f ? v : 0.f;
}

// ---------- graph mean pooling (batch sorted -> run-accumulate) ----------
__global__ __launch_bounds__(256)
void pool_kernel(const float* __restrict__ h, const int* __restrict__ batch,
                 int N, float* __restrict__ gsum, float* __restrict__ gcnt) {
    int c = threadIdx.x;
    int r0 = blockIdx.x * 128;
    int rend = min(r0 + 128, N);
    int curb = -1;
    float acc = 0.f;
    for (int r = r0; r < rend; ++r) {
        int b = batch[r];
        if (b != curb) {
            if (curb >= 0) atomicAdd(&gsum[curb * HIDC + c], acc);
            curb = b; acc = 0.f;
        }
        acc += h[(long)r * HIDC + c];
    }
    if (curb >= 0) atomicAdd(&gsum[curb * HIDC + c], acc);
    if (c == 0) {
        int prev = -1; float cnt = 0.f;
        for (int r = r0; r < rend; ++r) {
            int b = batch[r];
            if (b != prev) {
                if (prev >= 0) atomicAdd(&gcnt[prev], cnt);
                prev = b; cnt = 0.f;
            }
            cnt += 1.f;
        }
        if (prev >= 0) atomicAdd(&gcnt[prev], cnt);
    }
}

__global__ void gmean_kernel(float* __restrict__ gsum,
                             const float* __restrict__ gcnt) {
    int i = blockIdx.x * blockDim.x + threadIdx.x;
    if (i >= NG * HIDC) return;
    gsum[i] = gsum[i] / fmaxf(gcnt[i >> 8], 1.f);
}

// ---------- gproj[b,c] = sum_k gmean[b,k] * Wq1[256+k, c] ----------
__global__ __launch_bounds__(256)
void gproj_kernel(const float* __restrict__ gmean,
                  const float* __restrict__ Wq1, float* __restrict__ gproj) {
    int b = blockIdx.x, c = threadIdx.x;
    __shared__ float gm[HIDC];
    gm[c] = gmean[b * HIDC + c];
    __syncthreads();
    float acc = 0.f;
    for (int k = 0; k < HIDC; ++k)
        acc = fmaf(gm[k], Wq1[(long)(HIDC + k) * HIDC + c], acc);
    gproj[b * HIDC + c] = acc;
}

// ---------- head epilogue: hid = relu(hid + gproj[batch] + bq1) ----------
__global__ void head_epilogue_kernel(float* __restrict__ hid,
                                     const float* __restrict__ gproj,
                                     const int* __restrict__ batch,
                                     const float* __restrict__ bq1, int N) {
    long idx = (long)blockIdx.x * blockDim.x + threadIdx.x;
    if (idx >= (long)N * HIDC) return;
    int n = (int)(idx >> 8);
    int c = (int)(idx & (HIDC - 1));
    float v = hid[idx] + gproj[batch[n] * HIDC + c] + bq1[c];
    hid[idx] = v > 0.f ? v : 0.f;
}

// ---------- final q = hid @ Wq2 + bq2; also writes batch as float ----------
__global__ __launch_bounds__(256)
void q_kernel(const float* __restrict__ hid, const float* __restrict__ Wq2,
              const float* __restrict__ bq2, const int* __restrict__ batch,
              float* __restrict__ out, int N) {
    __shared__ float w[HIDC * 4];
    int t = threadIdx.x;
#pragma unroll
    for (int j = 0; j < 4; ++j) w[t + 256 * j] = Wq2[t + 256 * j];
    __syncthreads();
    int wid = t >> 6, lane = t & 63;
    int n = blockIdx.x * 4 + wid;
    if (n >= N) return;
    float a0 = 0, a1 = 0, a2 = 0, a3 = 0;
#pragma unroll
    for (int it = 0; it < 4; ++it) {
        int k = it * 64 + lane;
        float v = hid[(long)n * HIDC + k];
        a0 = fmaf(v, w[k * 4 + 0], a0);
        a1 = fmaf(v, w[k * 4 + 1], a1);
        a2 = fmaf(v, w[k * 4 + 2], a2);
        a3 = fmaf(v, w[k * 4 + 3], a3);
    }
    for (int o = 32; o > 0; o >>= 1) {
        a0 += __shfl_down(a0, o, 64);
        a1 += __shfl_down(a1, o, 64);
        a2 += __shfl_down(a2, o, 64);
        a3 += __shfl_down(a3, o, 64);
    }
    if (lane == 0) {
        out[(long)n * 4 + 0] = a0 + bq2[0];
        out[(long)n * 4 + 1] = a1 + bq2[1];
        out[(long)n * 4 + 2] = a2 + bq2[2];
        out[(long)n * 4 + 3] = a3 + bq2[3];
        out[(long)N * 4 + n] = (float)batch[n];  // output 1: batch_index
    }
}

extern "C" void kernel_launch(void* const* d_in, const int* in_sizes, int n_in,
                              void* d_out, int out_size, void* d_ws, size_t ws_size,
                              hipStream_t stream) {
    const float* x   = (const float*)d_in[0];
    const int*   ei  = (const int*)d_in[1];
    const int*   bat = (const int*)d_in[2];
    const float* W1  = (const float*)d_in[3];
    const float* as1 = (const float*)d_in[4];
    const float* ad1 = (const float*)d_in[5];
    // d_in[6] = b1: cancels through BatchNorm, unused
    const float* g1  = (const float*)d_in[7];
    const float* be1 = (const float*)d_in[8];
    const float* W2  = (const float*)d_in[9];
    const float* as2 = (const float*)d_in[10];
    const float* ad2 = (const float*)d_in[11];
    // d_in[12] = b2: cancels through BatchNorm, unused
    const float* g2  = (const float*)d_in[13];
    const float* be2 = (const float*)d_in[14];
    const float* Wq1 = (const float*)d_in[15];
    const float* bq1 = (const float*)d_in[16];
    const float* Wq2 = (const float*)d_in[17];
    const float* bq2 = (const float*)d_in[18];
    float* out = (float*)d_out;

    const int N = in_sizes[0] / F_IN;   // 50000
    const int E = in_sizes[1] / 2;      // 800000
    const int Etot = E + N;

    char* p = (char*)d_ws;
    float*    bufA  = (float*)p;    p += (size_t)N * HIDC * 4;   // 51.2 MB
    float*    bufB  = (float*)p;    p += (size_t)N * HIDC * 4;   // 51.2 MB
    float*    asrc  = (float*)p;    p += (size_t)N * 4 * 4;
    float*    adst  = (float*)p;    p += (size_t)N * 4 * 4;
    unsigned* menc  = (unsigned*)p; p += (size_t)N * 4 * 4;
    float*    denom = (float*)p;    p += (size_t)N * 4 * 4;
    float*    bnsum = (float*)p;    p += HIDC * 4;
    float*    bnsq  = (float*)p;    p += HIDC * 4;
    float*    gsum  = (float*)p;    p += NG * HIDC * 4;
    float*    gcnt  = (float*)p;    p += NG * 4;
    float*    gproj = (float*)p;    p += NG * HIDC * 4;

    dim3 gemmGrid(HIDC / 64, (N + 63) / 64);
    int edgeBlocks1 = (Etot + 255) / 256;
    int edgeBlocksW = (Etot + 3) / 4;   // wave-per-edge kernels
    int nodeBlocksW = (N + 3) / 4;
    long elemsH = (long)N * HIDC;

    // ===================== Layer 1 (GAT 128 -> 4x64) =====================
    gemm_kernel<<<gemmGrid, 256, 0, stream>>>(x, W1, bufA, N, F_IN, HIDC);
    hipMemsetAsync(menc, 0, (size_t)N * 4 * 4, stream);
    hipMemsetAsync(denom, 0, (size_t)N * 4 * 4, stream);
    hipMemsetAsync(bufB, 0, (size_t)N * HIDC * 4, stream);
    alpha_reduce_kernel<<<nodeBlocksW, 256, 0, stream>>>(bufA, as1, ad1, asrc, adst, N, 4);
    edge_max_kernel<<<edgeBlocks1, 256, 0, stream>>>(ei, E, N, asrc, adst, menc, 4);
    edge_denom_kernel<<<edgeBlocks1, 256, 0, stream>>>(ei, E, N, asrc, adst, menc, denom, 4);
    edge_scatter_kernel<<<edgeBlocksW, 256, 0, stream>>>(ei, E, N, asrc, adst, menc, denom, bufA, bufB, 4);
    hipMemsetAsync(bnsum, 0, HIDC * 4, stream);
    hipMemsetAsync(bnsq, 0, HIDC * 4, stream);
    bn_stats_kernel<<<(N + 127) / 128, 256, 0, stream>>>(bufB, N, bnsum, bnsq);
    bn_apply_relu_kernel<<<(elemsH + 255) / 256, 256, 0, stream>>>(bufB, N, bnsum, bnsq, g1, be1);

    // ===================== Layer 2 (GAT 256 -> 256, 1 head) ==============
    gemm_kernel<<<gemmGrid, 256, 0, stream>>>(bufB, W2, bufA, N, HIDC, HIDC);
    alpha_reduce_kernel<<<nodeBlocksW, 256, 0, stream>>>(bufA, as2, ad2, asrc, adst, N, 1);
    hipMemsetAsync(menc, 0, (size_t)N * 4, stream);
    hipMemsetAsync(denom, 0, (size_t)N * 4, stream);
    hipMemsetAsync(bufB, 0, (size_t)N * HIDC * 4, stream);   // after gemm consumed it
    edge_max_kernel<<<edgeBlocks1, 256, 0, stream>>>(ei, E, N, asrc, adst, menc, 1);
    edge_denom_kernel<<<edgeBlocks1, 256, 0, stream>>>(ei, E, N, asrc, adst, menc, denom, 1);
    edge_scatter_kernel<<<edgeBlocksW, 256, 0, stream>>>(ei, E, N, asrc, adst, menc, denom, bufA, bufB, 1);
    hipMemsetAsync(bnsum, 0, HIDC * 4, stream);
    hipMemsetAsync(bnsq, 0, HIDC * 4, stream);
    bn_stats_kernel<<<(N + 127) / 128, 256, 0, stream>>>(bufB, N, bnsum, bnsq);
    bn_apply_relu_kernel<<<(elemsH + 255) / 256, 256, 0, stream>>>(bufB, N, bnsum, bnsq, g2, be2);

    // ===================== Pool + head ===================================
    hipMemsetAsync(gsum, 0, NG * HIDC * 4, stream);
    hipMemsetAsync(gcnt, 0, NG * 4, stream);
    pool_kernel<<<(N + 127) / 128, 256, 0, stream>>>(bufB, bat, N, gsum, gcnt);
    gmean_kernel<<<(NG * HIDC + 255) / 256, 256, 0, stream>>>(gsum, gcnt);
    gproj_kernel<<<NG, 256, 0, stream>>>(gsum, Wq1, gproj);
    gemm_kernel<<<gemmGrid, 256, 0, stream>>>(bufB, Wq1, bufA, N, HIDC, HIDC); // top half of Wq1
    head_epilogue_kernel<<<(elemsH + 255) / 256, 256, 0, stream>>>(bufA, gproj, bat, bq1, N);
    q_kernel<<<nodeBlocksW, 256, 0, stream>>>(bufA, Wq2, bq2, bat, out, N);
}

// Round 2
// 1017.032 us; speedup vs baseline: 6.5760x; 6.5760x over previous
//
#include <hip/hip_runtime.h>
#include <hip/hip_bf16.h>
#include <math.h>

#define F_IN  128
#define HIDC  256
#define NG    8
#define EPS_BN 1e-5f

// ---------- GEMM: C[M,Ncol] = A[M,K] @ W[K,Ncol]; K%16==0, Ncol%64==0 ----
__global__ __launch_bounds__(256)
void gemm_kernel(const float* __restrict__ A, const float* __restrict__ W,
                 float* __restrict__ C, int M, int K, int Ncol) {
    const int BM = 64, BN = 64, BK = 16;
    __shared__ float As[16][64 + 1];
    __shared__ float Ws[16][64];
    int m0 = blockIdx.y * BM;
    int n0 = blockIdx.x * BN;
    int t = threadIdx.x;
    int tx = t % 16, ty = t / 16;
    float acc[4][4] = {};
    for (int k0 = 0; k0 < K; k0 += BK) {
#pragma unroll
        for (int j = 0; j < 4; ++j) {           // A tile: 64x16
            int i = t + 256 * j;
            int r = i / 16, c = i % 16;
            int gm = m0 + r;
            As[c][r] = (gm < M) ? A[(long)gm * K + k0 + c] : 0.f;
        }
#pragma unroll
        for (int j = 0; j < 4; ++j) {           // W tile: 16x64
            int i = t + 256 * j;
            int c = i / 64, n = i % 64;
            Ws[c][n] = W[(long)(k0 + c) * Ncol + n0 + n];
        }
        __syncthreads();
#pragma unroll
        for (int c = 0; c < BK; ++c) {
            float a[4], b[4];
#pragma unroll
            for (int i = 0; i < 4; ++i) a[i] = As[c][ty * 4 + i];
#pragma unroll
            for (int j = 0; j < 4; ++j) b[j] = Ws[c][tx * 4 + j];
#pragma unroll
            for (int i = 0; i < 4; ++i)
#pragma unroll
                for (int j = 0; j < 4; ++j)
                    acc[i][j] = fmaf(a[i], b[j], acc[i][j]);
        }
        __syncthreads();
    }
#pragma unroll
    for (int i = 0; i < 4; ++i) {
        int gm = m0 + ty * 4 + i;
        if (gm >= M) continue;
#pragma unroll
        for (int j = 0; j < 4; ++j)
            C[(long)gm * Ncol + n0 + tx * 4 + j] = acc[i][j];
    }
}

// ---------- per-node attention logits: asrc[n,h] = sum_d h[n,h,d]*wsrc[h,d]
__global__ __launch_bounds__(256)
void alpha_reduce_kernel(const float* __restrict__ h,
                         const float* __restrict__ wsrc,
                         const float* __restrict__ wdst,
                         float* __restrict__ asrc, float* __restrict__ adst,
                         int N, int H) {
    int wid = threadIdx.x >> 6;
    int lane = threadIdx.x & 63;
    int n = blockIdx.x * 4 + wid;
    if (n >= N) return;
    float ps[4], pd[4];
#pragma unroll
    for (int j = 0; j < 4; ++j) {
        int c = j * 64 + lane;
        float hv = h[(long)n * HIDC + c];
        ps[j] = hv * wsrc[c];
        pd[j] = hv * wdst[c];
    }
    if (H == 1) {
        float s = ps[0] + ps[1] + ps[2] + ps[3];
        float d = pd[0] + pd[1] + pd[2] + pd[3];
        for (int o = 32; o > 0; o >>= 1) {
            s += __shfl_down(s, o, 64);
            d += __shfl_down(d, o, 64);
        }
        if (lane == 0) { asrc[n] = s; adst[n] = d; }
    } else {  // H == 4, D == 64: each j IS one head
#pragma unroll
        for (int j = 0; j < 4; ++j) {
            float s = ps[j], d = pd[j];
            for (int o = 32; o > 0; o >>= 1) {
                s += __shfl_down(s, o, 64);
                d += __shfl_down(d, o, 64);
            }
            if (lane == 0) { asrc[n * 4 + j] = s; adst[n * 4 + j] = d; }
        }
    }
}

// =================== CSR build (by destination), reused for both layers ===
__global__ void deg_kernel(const int* __restrict__ ei, int E, int N,
                           int* __restrict__ deg) {
    int e = blockIdx.x * blockDim.x + threadIdx.x;
    if (e >= E + N) return;
    int d = (e < E) ? ei[E + e] : (e - E);
    atomicAdd(&deg[d], 1);
}

// 3-phase exclusive scan over deg[N] -> rowptr[N+1]
__global__ __launch_bounds__(256)
void scan_phase1(const int* __restrict__ deg, int* __restrict__ part,
                 int* __restrict__ bsum, int N) {
    __shared__ int tmp[256];
    int i = blockIdx.x * 256 + threadIdx.x;
    int v = (i < N) ? deg[i] : 0;
    tmp[threadIdx.x] = v;
    __syncthreads();
    for (int off = 1; off < 256; off <<= 1) {
        int t = (threadIdx.x >= off) ? tmp[threadIdx.x - off] : 0;
        __syncthreads();
        tmp[threadIdx.x] += t;
        __syncthreads();
    }
    if (i < N) part[i] = tmp[threadIdx.x];            // inclusive within block
    if (threadIdx.x == 255) bsum[blockIdx.x] = tmp[255];
}
__global__ __launch_bounds__(256)
void scan_phase2(int* __restrict__ bsum, int nb) {
    __shared__ int tmp[256];
    int v = (threadIdx.x < nb) ? bsum[threadIdx.x] : 0;
    tmp[threadIdx.x] = v;
    __syncthreads();
    for (int off = 1; off < 256; off <<= 1) {
        int t = (threadIdx.x >= off) ? tmp[threadIdx.x - off] : 0;
        __syncthreads();
        tmp[threadIdx.x] += t;
        __syncthreads();
    }
    if (threadIdx.x < nb)
        bsum[threadIdx.x] = threadIdx.x ? tmp[threadIdx.x - 1] : 0;  // exclusive
}
__global__ __launch_bounds__(256)
void scan_phase3(const int* __restrict__ part, const int* __restrict__ bsum,
                 int* __restrict__ rowptr, int N) {
    int i = blockIdx.x * 256 + threadIdx.x;
    if (i < N) rowptr[i + 1] = part[i] + bsum[blockIdx.x];
    if (i == 0) rowptr[0] = 0;
}

__global__ void fill_kernel(const int* __restrict__ ei, int E, int N,
                            const int* __restrict__ rowptr,
                            int* __restrict__ cur, int* __restrict__ csr_src) {
    int e = blockIdx.x * blockDim.x + threadIdx.x;
    if (e >= E + N) return;
    int s = (e < E) ? ei[e] : (e - E);
    int d = (e < E) ? ei[E + e] : (e - E);
    int pos = rowptr[d] + atomicAdd(&cur[d], 1);
    csr_src[pos] = s;
}

// ========== fused GAT edge-softmax + aggregation: wave per dst node =======
template <int H>
__global__ __launch_bounds__(256)
void gat_gather_kernel(const int* __restrict__ rowptr,
                       const int* __restrict__ csr_src,
                       const float* __restrict__ asrc,
                       const float* __restrict__ adst,
                       const float* __restrict__ h,
                       float* __restrict__ agg, int N) {
    const int D = HIDC / H;
    int wid = threadIdx.x >> 6, lane = threadIdx.x & 63;
    int n = blockIdx.x * 4 + wid;
    if (n >= N) return;
    int start = rowptr[n], end = rowptr[n + 1];
    float ad[H];
#pragma unroll
    for (int hh = 0; hh < H; ++hh) ad[hh] = adst[n * H + hh];

    // pass A: segment max per head
    float mh[H];
#pragma unroll
    for (int hh = 0; hh < H; ++hh) mh[hh] = -INFINITY;
    for (int i = start + lane; i < end; i += 64) {
        int s = csr_src[i];
#pragma unroll
        for (int hh = 0; hh < H; ++hh) {
            float v = asrc[s * H + hh] + ad[hh];
            v = (v >= 0.f) ? v : 0.2f * v;
            mh[hh] = fmaxf(mh[hh], v);
        }
    }
#pragma unroll
    for (int hh = 0; hh < H; ++hh)
        for (int o = 32; o > 0; o >>= 1)
            mh[hh] = fmaxf(mh[hh], __shfl_xor(mh[hh], o, 64));

    // pass B: softmax denominator per head
    float dh[H] = {};
    for (int i = start + lane; i < end; i += 64) {
        int s = csr_src[i];
#pragma unroll
        for (int hh = 0; hh < H; ++hh) {
            float v = asrc[s * H + hh] + ad[hh];
            v = (v >= 0.f) ? v : 0.2f * v;
            dh[hh] += __expf(v - mh[hh]);
        }
    }
#pragma unroll
    for (int hh = 0; hh < H; ++hh)
        for (int o = 32; o > 0; o >>= 1)
            dh[hh] += __shfl_xor(dh[hh], o, 64);
    float inv_dh[H];
#pragma unroll
    for (int hh = 0; hh < H; ++hh) inv_dh[hh] = 1.f / (dh[hh] + 1e-16f);

    // pass C: chunked alpha-weighted accumulation (channels across lanes)
    float acc0 = 0.f, acc1 = 0.f, acc2 = 0.f, acc3 = 0.f;
    int head = (lane * 4) / D;  // H=4 -> lane/16 ; H=1 -> 0
    for (int base = start; base < end; base += 64) {
        int cnt = min(64, end - base);
        int my_s = 0;
        float a0 = 0.f, a1 = 0.f, a2 = 0.f, a3 = 0.f;
        if (lane < cnt) {
            my_s = csr_src[base + lane];
            float av[H];
#pragma unroll
            for (int hh = 0; hh < H; ++hh) {
                float v = asrc[my_s * H + hh] + ad[hh];
                v = (v >= 0.f) ? v : 0.2f * v;
                av[hh] = __expf(v - mh[hh]) * inv_dh[hh];
            }
            a0 = av[0];
            if (H == 4) { a1 = av[1 % H]; a2 = av[2 % H]; a3 = av[3 % H]; }
        }
        for (int j = 0; j < cnt; ++j) {
            int s = __shfl(my_s, j, 64);
            float al;
            if (H == 1) {
                al = __shfl(a0, j, 64);
            } else {
                float v0 = __shfl(a0, j, 64);
                float v1 = __shfl(a1, j, 64);
                float v2 = __shfl(a2, j, 64);
                float v3 = __shfl(a3, j, 64);
                al = (head == 0) ? v0 : (head == 1) ? v1 : (head == 2) ? v2 : v3;
            }
            const float4 hv = ((const float4*)(h + (long)s * HIDC))[lane];
            acc0 = fmaf(hv.x, al, acc0);
            acc1 = fmaf(hv.y, al, acc1);
            acc2 = fmaf(hv.z, al, acc2);
            acc3 = fmaf(hv.w, al, acc3);
        }
    }
    float4 o4 = make_float4(acc0, acc1, acc2, acc3);
    ((float4*)(agg + (long)n * HIDC))[lane] = o4;
}

// ---------- BatchNorm stats (per-channel sum / sumsq) ----------
__global__ __launch_bounds__(256)
void bn_stats_kernel(const float* __restrict__ h, int N,
                     float* __restrict__ sum, float* __restrict__ sumsq) {
    int c = threadIdx.x;
    int r0 = blockIdx.x * 128;
    int rend = min(r0 + 128, N);
    float s = 0.f, q = 0.f;
    for (int r = r0; r < rend; ++r) {
        float v = h[(long)r * HIDC + c];
        s += v;
        q += v * v;
    }
    atomicAdd(&sum[c], s);
    atomicAdd(&sumsq[c], q);
}

// ---------- BN apply + relu (in place); bias cancels through BN ----------
__global__ void bn_apply_relu_kernel(float* __restrict__ h, int N,
                                     const float* __restrict__ sum,
                                     const float* __restrict__ sumsq,
                                     const float* __restrict__ gamma,
                                     const float* __restrict__ beta) {
    long idx = (long)blockIdx.x * blockDim.x + threadIdx.x;
    long total = (long)N * HIDC;
    if (idx >= total) return;
    int c = (int)(idx & (HIDC - 1));
    float invN = 1.f / (float)N;
    float mu = sum[c] * invN;
    float var = sumsq[c] * invN - mu * mu;
    float inv = rsqrtf(var + EPS_BN);
    float v = gamma[c] * (h[idx] - mu) * inv + beta[c];
    h[idx] = v > 0.f ? v : 0.f;
}

// ---------- graph mean pooling (batch sorted -> run-accumulate) ----------
__global__ __launch_bounds__(256)
void pool_kernel(const float* __restrict__ h, const int* __restrict__ batch,
                 int N, float* __restrict__ gsum, float* __restrict__ gcnt) {
    int c = threadIdx.x;
    int r0 = blockIdx.x * 128;
    int rend = min(r0 + 128, N);
    int curb = -1;
    float acc = 0.f;
    for (int r = r0; r < rend; ++r) {
        int b = batch[r];
        if (b != curb) {
            if (curb >= 0) atomicAdd(&gsum[curb * HIDC + c], acc);
            curb = b; acc = 0.f;
        }
        acc += h[(long)r * HIDC + c];
    }
    if (curb >= 0) atomicAdd(&gsum[curb * HIDC + c], acc);
    if (c == 0) {
        int prev = -1; float cnt = 0.f;
        for (int r = r0; r < rend; ++r) {
            int b = batch[r];
            if (b != prev) {
                if (prev >= 0) atomicAdd(&gcnt[prev], cnt);
                prev = b; cnt = 0.f;
            }
            cnt += 1.f;
        }
        if (prev >= 0) atomicAdd(&gcnt[prev], cnt);
    }
}

__global__ void gmean_kernel(float* __restrict__ gsum,
                             const float* __restrict__ gcnt) {
    int i = blockIdx.x * blockDim.x + threadIdx.x;
    if (i >= NG * HIDC) return;
    gsum[i] = gsum[i] / fmaxf(gcnt[i >> 8], 1.f);
}

// ---------- gproj[b,c] = sum_k gmean[b,k] * Wq1[256+k, c] ----------
__global__ __launch_bounds__(256)
void gproj_kernel(const float* __restrict__ gmean,
                  const float* __restrict__ Wq1, float* __restrict__ gproj) {
    int b = blockIdx.x, c = threadIdx.x;
    __shared__ float gm[HIDC];
    gm[c] = gmean[b * HIDC + c];
    __syncthreads();
    float acc = 0.f;
    for (int k = 0; k < HIDC; ++k)
        acc = fmaf(gm[k], Wq1[(long)(HIDC + k) * HIDC + c], acc);
    gproj[b * HIDC + c] = acc;
}

// ---------- head epilogue: hid = relu(hid + gproj[batch] + bq1) ----------
__global__ void head_epilogue_kernel(float* __restrict__ hid,
                                     const float* __restrict__ gproj,
                                     const int* __restrict__ batch,
                                     const float* __restrict__ bq1, int N) {
    long idx = (long)blockIdx.x * blockDim.x + threadIdx.x;
    if (idx >= (long)N * HIDC) return;
    int n = (int)(idx >> 8);
    int c = (int)(idx & (HIDC - 1));
    float v = hid[idx] + gproj[batch[n] * HIDC + c] + bq1[c];
    hid[idx] = v > 0.f ? v : 0.f;
}

// ---------- final q = hid @ Wq2 + bq2; also writes batch as float ----------
__global__ __launch_bounds__(256)
void q_kernel(const float* __restrict__ hid, const float* __restrict__ Wq2,
              const float* __restrict__ bq2, const int* __restrict__ batch,
              float* __restrict__ out, int N) {
    __shared__ float w[HIDC * 4];
    int t = threadIdx.x;
#pragma unroll
    for (int j = 0; j < 4; ++j) w[t + 256 * j] = Wq2[t + 256 * j];
    __syncthreads();
    int wid = t >> 6, lane = t & 63;
    int n = blockIdx.x * 4 + wid;
    if (n >= N) return;
    float a0 = 0, a1 = 0, a2 = 0, a3 = 0;
#pragma unroll
    for (int it = 0; it < 4; ++it) {
        int k = it * 64 + lane;
        float v = hid[(long)n * HIDC + k];
        a0 = fmaf(v, w[k * 4 + 0], a0);
        a1 = fmaf(v, w[k * 4 + 1], a1);
        a2 = fmaf(v, w[k * 4 + 2], a2);
        a3 = fmaf(v, w[k * 4 + 3], a3);
    }
    for (int o = 32; o > 0; o >>= 1) {
        a0 += __shfl_down(a0, o, 64);
        a1 += __shfl_down(a1, o, 64);
        a2 += __shfl_down(a2, o, 64);
        a3 += __shfl_down(a3, o, 64);
    }
    if (lane == 0) {
        out[(long)n * 4 + 0] = a0 + bq2[0];
        out[(long)n * 4 + 1] = a1 + bq2[1];
        out[(long)n * 4 + 2] = a2 + bq2[2];
        out[(long)n * 4 + 3] = a3 + bq2[3];
        out[(long)N * 4 + n] = (float)batch[n];  // output 1: batch_index
    }
}

extern "C" void kernel_launch(void* const* d_in, const int* in_sizes, int n_in,
                              void* d_out, int out_size, void* d_ws, size_t ws_size,
                              hipStream_t stream) {
    const float* x   = (const float*)d_in[0];
    const int*   ei  = (const int*)d_in[1];
    const int*   bat = (const int*)d_in[2];
    const float* W1  = (const float*)d_in[3];
    const float* as1 = (const float*)d_in[4];
    const float* ad1 = (const float*)d_in[5];
    // d_in[6] = b1: cancels through BatchNorm, unused
    const float* g1  = (const float*)d_in[7];
    const float* be1 = (const float*)d_in[8];
    const float* W2  = (const float*)d_in[9];
    const float* as2 = (const float*)d_in[10];
    const float* ad2 = (const float*)d_in[11];
    // d_in[12] = b2: cancels through BatchNorm, unused
    const float* g2  = (const float*)d_in[13];
    const float* be2 = (const float*)d_in[14];
    const float* Wq1 = (const float*)d_in[15];
    const float* bq1 = (const float*)d_in[16];
    const float* Wq2 = (const float*)d_in[17];
    const float* bq2 = (const float*)d_in[18];
    float* out = (float*)d_out;

    const int N = in_sizes[0] / F_IN;   // 50000
    const int E = in_sizes[1] / 2;      // 800000
    const int Etot = E + N;
    const int nb = (N + 255) / 256;     // scan blocks (196)

    char* p = (char*)d_ws;
    float* bufA   = (float*)p;  p += (size_t)N * HIDC * 4;   // 51.2 MB
    float* bufB   = (float*)p;  p += (size_t)N * HIDC * 4;   // 51.2 MB
    float* asrc   = (float*)p;  p += (size_t)N * 4 * 4;
    float* adst   = (float*)p;  p += (size_t)N * 4 * 4;
    int*   rowptr = (int*)p;    p += (size_t)(N + 1) * 4;
    int*   csr_src= (int*)p;    p += (size_t)Etot * 4;
    int*   cur    = (int*)p;    p += (size_t)N * 4;          // deg, then fill cursor
    int*   part   = (int*)p;    p += (size_t)N * 4;
    int*   bsum   = (int*)p;    p += (size_t)nb * 4;
    float* bnsum  = (float*)p;  p += HIDC * 4;
    float* bnsq   = (float*)p;  p += HIDC * 4;
    float* gsum   = (float*)p;  p += NG * HIDC * 4;
    float* gcnt   = (float*)p;  p += NG * 4;
    float* gproj  = (float*)p;  p += NG * HIDC * 4;

    dim3 gemmGrid(HIDC / 64, (N + 63) / 64);
    int edgeBlocks = (Etot + 255) / 256;
    int nodeBlocksW = (N + 3) / 4;
    long elemsH = (long)N * HIDC;

    // ===================== CSR build (once, reused by both layers) =======
    hipMemsetAsync(cur, 0, (size_t)N * 4, stream);
    deg_kernel<<<edgeBlocks, 256, 0, stream>>>(ei, E, N, cur);
    scan_phase1<<<nb, 256, 0, stream>>>(cur, part, bsum, N);
    scan_phase2<<<1, 256, 0, stream>>>(bsum, nb);
    scan_phase3<<<nb, 256, 0, stream>>>(part, bsum, rowptr, N);
    hipMemsetAsync(cur, 0, (size_t)N * 4, stream);
    fill_kernel<<<edgeBlocks, 256, 0, stream>>>(ei, E, N, rowptr, cur, csr_src);

    // ===================== Layer 1 (GAT 128 -> 4x64) =====================
    gemm_kernel<<<gemmGrid, 256, 0, stream>>>(x, W1, bufA, N, F_IN, HIDC);
    alpha_reduce_kernel<<<nodeBlocksW, 256, 0, stream>>>(bufA, as1, ad1, asrc, adst, N, 4);
    gat_gather_kernel<4><<<nodeBlocksW, 256, 0, stream>>>(rowptr, csr_src, asrc, adst, bufA, bufB, N);
    hipMemsetAsync(bnsum, 0, HIDC * 4, stream);
    hipMemsetAsync(bnsq, 0, HIDC * 4, stream);
    bn_stats_kernel<<<(N + 127) / 128, 256, 0, stream>>>(bufB, N, bnsum, bnsq);
    bn_apply_relu_kernel<<<(elemsH + 255) / 256, 256, 0, stream>>>(bufB, N, bnsum, bnsq, g1, be1);

    // ===================== Layer 2 (GAT 256 -> 256, 1 head) ==============
    gemm_kernel<<<gemmGrid, 256, 0, stream>>>(bufB, W2, bufA, N, HIDC, HIDC);
    alpha_reduce_kernel<<<nodeBlocksW, 256, 0, stream>>>(bufA, as2, ad2, asrc, adst, N, 1);
    gat_gather_kernel<1><<<nodeBlocksW, 256, 0, stream>>>(rowptr, csr_src, asrc, adst, bufA, bufB, N);
    hipMemsetAsync(bnsum, 0, HIDC * 4, stream);
    hipMemsetAsync(bnsq, 0, HIDC * 4, stream);
    bn_stats_kernel<<<(N + 127) / 128, 256, 0, stream>>>(bufB, N, bnsum, bnsq);
    bn_apply_relu_kernel<<<(elemsH + 255) / 256, 256, 0, stream>>>(bufB, N, bnsum, bnsq, g2, be2);

    // ===================== Pool + head ===================================
    hipMemsetAsync(gsum, 0, NG * HIDC * 4, stream);
    hipMemsetAsync(gcnt, 0, NG * 4, stream);
    pool_kernel<<<(N + 127) / 128, 256, 0, stream>>>(bufB, bat, N, gsum, gcnt);
    gmean_kernel<<<(NG * HIDC + 255) / 256, 256, 0, stream>>>(gsum, gcnt);
    gproj_kernel<<<NG, 256, 0, stream>>>(gsum, Wq1, gproj);
    gemm_kernel<<<gemmGrid, 256, 0, stream>>>(bufB, Wq1, bufA, N, HIDC, HIDC); // top half of Wq1
    head_epilogue_kernel<<<(elemsH + 255) / 256, 256, 0, stream>>>(bufA, gproj, bat, bq1, N);
    q_kernel<<<nodeBlocksW, 256, 0, stream>>>(bufA, Wq2, bq2, bat, out, N);
}

// Round 3
// 805.809 us; speedup vs baseline: 8.2997x; 1.2621x over previous
//
#include <hip/hip_runtime.h>
#include <hip/hip_bf16.h>
#include <math.h>

#define F_IN  128
#define HIDC  256
#define NG    8
#define EPS_BN 1e-5f

typedef unsigned short u16;
typedef unsigned int   u32;
typedef __attribute__((ext_vector_type(8))) short bf16x8;
typedef __attribute__((ext_vector_type(4))) float f32x4;

// ---------- bf16 helpers ----------
static __device__ __forceinline__ float b2f(u16 u) {
    return __uint_as_float((u32)u << 16);
}
static __device__ __forceinline__ u16 f2b(float f) {   // RNE
    u32 u = __float_as_uint(f);
    u32 r = (u + 0x7fffu + ((u >> 16) & 1u)) >> 16;
    return (u16)r;
}
static __device__ __forceinline__ u32 pack2(float a, float b) {
    return (u32)f2b(a) | ((u32)f2b(b) << 16);
}

// ---------- prep: fp32 -> bf16 (paired) ----------
__global__ void f2b2_kernel(const float* __restrict__ in, u32* __restrict__ out, int npair) {
    int i = blockIdx.x * 256 + threadIdx.x;
    if (i >= npair) return;
    float2 v = ((const float2*)in)[i];
    out[i] = pack2(v.x, v.y);
}

// ---------- prep: W [K][Ncol] fp32 -> WT [Ncol][K] bf16 ----------
__global__ void wt_kernel(const float* __restrict__ W, u16* __restrict__ WT,
                          int K, int Ncol) {
    int i = blockIdx.x * 256 + threadIdx.x;
    if (i >= K * Ncol) return;
    int n = i / K, k = i % K;
    WT[i] = f2b(W[(long)k * Ncol + n]);
}

// ---------- MFMA GEMM: C[M,256] = A[M,K] @ B, B given as WT[256][K] bf16 --
// wave computes 16 rows x 128 cols; block = 4 waves (64 rows); grid.x = 2.
template <int K>
__global__ __launch_bounds__(256)
void gemm_mfma_kernel(const u16* __restrict__ A, const u16* __restrict__ WT,
                      u16* __restrict__ C, int M) {
    int wid = threadIdx.x >> 6, lane = threadIdx.x & 63;
    int m0 = (blockIdx.y * 4 + wid) * 16;
    if (m0 >= M) return;
    int n0 = blockIdx.x * 128;
    int row = lane & 15, quad = lane >> 4;
    const u16* Ap = A + (size_t)(m0 + row) * K + quad * 8;
    f32x4 acc[8];
#pragma unroll
    for (int t = 0; t < 8; ++t) acc[t] = (f32x4){0.f, 0.f, 0.f, 0.f};
#pragma unroll
    for (int k0 = 0; k0 < K; k0 += 32) {
        bf16x8 a = *(const bf16x8*)(Ap + k0);
#pragma unroll
        for (int t = 0; t < 8; ++t) {
            const u16* Bp = WT + (size_t)(n0 + t * 16 + row) * K + k0 + quad * 8;
            bf16x8 b = *(const bf16x8*)Bp;
            acc[t] = __builtin_amdgcn_mfma_f32_16x16x32_bf16(a, b, acc[t], 0, 0, 0);
        }
    }
    // C/D layout: col = lane&15, row = quad*4 + reg
#pragma unroll
    for (int t = 0; t < 8; ++t) {
#pragma unroll
        for (int r = 0; r < 4; ++r) {
            int m = m0 + quad * 4 + r;
            int n = n0 + t * 16 + row;
            C[(size_t)m * HIDC + n] = f2b(acc[t][r]);
        }
    }
}

// ---------- per-node attention logits (bf16 h) ----------
__global__ __launch_bounds__(256)
void alpha_reduce_kernel(const u16* __restrict__ h,
                         const float* __restrict__ wsrc,
                         const float* __restrict__ wdst,
                         float* __restrict__ asrc, float* __restrict__ adst,
                         int N, int H) {
    int wid = threadIdx.x >> 6;
    int lane = threadIdx.x & 63;
    int n = blockIdx.x * 4 + wid;
    if (n >= N) return;
    float ps[4], pd[4];
#pragma unroll
    for (int j = 0; j < 4; ++j) {
        int c = j * 64 + lane;
        float hv = b2f(h[(long)n * HIDC + c]);
        ps[j] = hv * wsrc[c];
        pd[j] = hv * wdst[c];
    }
    if (H == 1) {
        float s = ps[0] + ps[1] + ps[2] + ps[3];
        float d = pd[0] + pd[1] + pd[2] + pd[3];
        for (int o = 32; o > 0; o >>= 1) {
            s += __shfl_down(s, o, 64);
            d += __shfl_down(d, o, 64);
        }
        if (lane == 0) { asrc[n] = s; adst[n] = d; }
    } else {
#pragma unroll
        for (int j = 0; j < 4; ++j) {
            float s = ps[j], d = pd[j];
            for (int o = 32; o > 0; o >>= 1) {
                s += __shfl_down(s, o, 64);
                d += __shfl_down(d, o, 64);
            }
            if (lane == 0) { asrc[n * 4 + j] = s; adst[n * 4 + j] = d; }
        }
    }
}

// =================== CSR build (by destination), reused for both layers ===
__global__ void deg_kernel(const int* __restrict__ ei, int E, int N,
                           int* __restrict__ deg) {
    int e = blockIdx.x * blockDim.x + threadIdx.x;
    if (e >= E + N) return;
    int d = (e < E) ? ei[E + e] : (e - E);
    atomicAdd(&deg[d], 1);
}

__global__ __launch_bounds__(256)
void scan_phase1(const int* __restrict__ deg, int* __restrict__ part,
                 int* __restrict__ bsum, int N) {
    __shared__ int tmp[256];
    int i = blockIdx.x * 256 + threadIdx.x;
    int v = (i < N) ? deg[i] : 0;
    tmp[threadIdx.x] = v;
    __syncthreads();
    for (int off = 1; off < 256; off <<= 1) {
        int t = (threadIdx.x >= off) ? tmp[threadIdx.x - off] : 0;
        __syncthreads();
        tmp[threadIdx.x] += t;
        __syncthreads();
    }
    if (i < N) part[i] = tmp[threadIdx.x];
    if (threadIdx.x == 255) bsum[blockIdx.x] = tmp[255];
}
__global__ __launch_bounds__(256)
void scan_phase2(int* __restrict__ bsum, int nb) {
    __shared__ int tmp[256];
    int v = (threadIdx.x < nb) ? bsum[threadIdx.x] : 0;
    tmp[threadIdx.x] = v;
    __syncthreads();
    for (int off = 1; off < 256; off <<= 1) {
        int t = (threadIdx.x >= off) ? tmp[threadIdx.x - off] : 0;
        __syncthreads();
        tmp[threadIdx.x] += t;
        __syncthreads();
    }
    if (threadIdx.x < nb)
        bsum[threadIdx.x] = threadIdx.x ? tmp[threadIdx.x - 1] : 0;
}
__global__ __launch_bounds__(256)
void scan_phase3(const int* __restrict__ part, const int* __restrict__ bsum,
                 int* __restrict__ rowptr, int N) {
    int i = blockIdx.x * 256 + threadIdx.x;
    if (i < N) rowptr[i + 1] = part[i] + bsum[blockIdx.x];
    if (i == 0) rowptr[0] = 0;
}

__global__ void fill_kernel(const int* __restrict__ ei, int E, int N,
                            const int* __restrict__ rowptr,
                            int* __restrict__ cur, int* __restrict__ csr_src) {
    int e = blockIdx.x * blockDim.x + threadIdx.x;
    if (e >= E + N) return;
    int s = (e < E) ? ei[e] : (e - E);
    int d = (e < E) ? ei[E + e] : (e - E);
    int pos = rowptr[d] + atomicAdd(&cur[d], 1);
    csr_src[pos] = s;
}

// ========== fused GAT edge-softmax + aggregation (bf16 h, bf16 out) =======
template <int H>
__global__ __launch_bounds__(256)
void gat_gather_kernel(const int* __restrict__ rowptr,
                       const int* __restrict__ csr_src,
                       const float* __restrict__ asrc,
                       const float* __restrict__ adst,
                       const u16* __restrict__ h,
                       u16* __restrict__ agg, int N) {
    int wid = threadIdx.x >> 6, lane = threadIdx.x & 63;
    int n = blockIdx.x * 4 + wid;
    if (n >= N) return;
    int start = rowptr[n], end = rowptr[n + 1];
    float ad[H];
#pragma unroll
    for (int hh = 0; hh < H; ++hh) ad[hh] = adst[n * H + hh];

    // pass A: segment max per head
    float mh[H];
#pragma unroll
    for (int hh = 0; hh < H; ++hh) mh[hh] = -INFINITY;
    for (int i = start + lane; i < end; i += 64) {
        int s = csr_src[i];
#pragma unroll
        for (int hh = 0; hh < H; ++hh) {
            float v = asrc[s * H + hh] + ad[hh];
            v = (v >= 0.f) ? v : 0.2f * v;
            mh[hh] = fmaxf(mh[hh], v);
        }
    }
#pragma unroll
    for (int hh = 0; hh < H; ++hh)
        for (int o = 32; o > 0; o >>= 1)
            mh[hh] = fmaxf(mh[hh], __shfl_xor(mh[hh], o, 64));

    // pass B: softmax denominator per head
    float dh[H] = {};
    for (int i = start + lane; i < end; i += 64) {
        int s = csr_src[i];
#pragma unroll
        for (int hh = 0; hh < H; ++hh) {
            float v = asrc[s * H + hh] + ad[hh];
            v = (v >= 0.f) ? v : 0.2f * v;
            dh[hh] += __expf(v - mh[hh]);
        }
    }
#pragma unroll
    for (int hh = 0; hh < H; ++hh)
        for (int o = 32; o > 0; o >>= 1)
            dh[hh] += __shfl_xor(dh[hh], o, 64);
    float inv_dh[H];
#pragma unroll
    for (int hh = 0; hh < H; ++hh) inv_dh[hh] = 1.f / (dh[hh] + 1e-16f);

    // pass C: alpha-weighted accumulation; lane owns 4 channels (uint2 bf16)
    float acc0 = 0.f, acc1 = 0.f, acc2 = 0.f, acc3 = 0.f;
    int head = (H == 4) ? (lane >> 4) : 0;   // 4 ch/lane, 64 ch/head
    for (int base = start; base < end; base += 64) {
        int cnt = min(64, end - base);
        int my_s = 0;
        float a0 = 0.f, a1 = 0.f, a2 = 0.f, a3 = 0.f;
        if (lane < cnt) {
            my_s = csr_src[base + lane];
            float av[H];
#pragma unroll
            for (int hh = 0; hh < H; ++hh) {
                float v = asrc[my_s * H + hh] + ad[hh];
                v = (v >= 0.f) ? v : 0.2f * v;
                av[hh] = __expf(v - mh[hh]) * inv_dh[hh];
            }
            a0 = av[0];
            if (H == 4) { a1 = av[1 % H]; a2 = av[2 % H]; a3 = av[3 % H]; }
        }
        for (int j = 0; j < cnt; ++j) {
            int s = __shfl(my_s, j, 64);
            float al;
            if (H == 1) {
                al = __shfl(a0, j, 64);
            } else {
                float v0 = __shfl(a0, j, 64);
                float v1 = __shfl(a1, j, 64);
                float v2 = __shfl(a2, j, 64);
                float v3 = __shfl(a3, j, 64);
                al = (head == 0) ? v0 : (head == 1) ? v1 : (head == 2) ? v2 : v3;
            }
            uint2 hv = ((const uint2*)(h + (size_t)s * HIDC))[lane];
            acc0 = fmaf(__uint_as_float(hv.x << 16), al, acc0);
            acc1 = fmaf(__uint_as_float(hv.x & 0xffff0000u), al, acc1);
            acc2 = fmaf(__uint_as_float(hv.y << 16), al, acc2);
            acc3 = fmaf(__uint_as_float(hv.y & 0xffff0000u), al, acc3);
        }
    }
    uint2 o;
    o.x = pack2(acc0, acc1);
    o.y = pack2(acc2, acc3);
    ((uint2*)(agg + (size_t)n * HIDC))[lane] = o;
}

// ---------- BatchNorm stats (bf16 in, fp32 accumulate) ----------
__global__ __launch_bounds__(256)
void bn_stats_kernel(const u16* __restrict__ h, int N,
                     float* __restrict__ sum, float* __restrict__ sumsq) {
    int c = threadIdx.x;
    int r0 = blockIdx.x * 128;
    int rend = min(r0 + 128, N);
    float s = 0.f, q = 0.f;
    for (int r = r0; r < rend; ++r) {
        float v = b2f(h[(long)r * HIDC + c]);
        s += v;
        q += v * v;
    }
    atomicAdd(&sum[c], s);
    atomicAdd(&sumsq[c], q);
}

// ---------- BN apply + relu: bf16 in -> bf16 out (2 ch per thread) -------
__global__ void bn_apply_relu_kernel(const u32* __restrict__ in,
                                     u32* __restrict__ out, int N,
                                     const float* __restrict__ sum,
                                     const float* __restrict__ sumsq,
                                     const float* __restrict__ gamma,
                                     const float* __restrict__ beta) {
    int idx = blockIdx.x * 256 + threadIdx.x;
    if (idx >= N * (HIDC / 2)) return;
    int c0 = (idx & (HIDC / 2 - 1)) * 2;
    u32 v = in[idx];
    float invN = 1.f / (float)N;
    float r[2];
#pragma unroll
    for (int j = 0; j < 2; ++j) {
        int c = c0 + j;
        float mu = sum[c] * invN;
        float var = sumsq[c] * invN - mu * mu;
        float inv = rsqrtf(var + EPS_BN);
        float x = (j == 0) ? __uint_as_float(v << 16)
                           : __uint_as_float(v & 0xffff0000u);
        float y = gamma[c] * (x - mu) * inv + beta[c];
        r[j] = y > 0.f ? y : 0.f;
    }
    out[idx] = pack2(r[0], r[1]);
}

// ---------- graph mean pooling (bf16 in) ----------
__global__ __launch_bounds__(256)
void pool_kernel(const u16* __restrict__ h, const int* __restrict__ batch,
                 int N, float* __restrict__ gsum, float* __restrict__ gcnt) {
    int c = threadIdx.x;
    int r0 = blockIdx.x * 128;
    int rend = min(r0 + 128, N);
    int curb = -1;
    float acc = 0.f;
    for (int r = r0; r < rend; ++r) {
        int b = batch[r];
        if (b != curb) {
            if (curb >= 0) atomicAdd(&gsum[curb * HIDC + c], acc);
            curb = b; acc = 0.f;
        }
        acc += b2f(h[(long)r * HIDC + c]);
    }
    if (curb >= 0) atomicAdd(&gsum[curb * HIDC + c], acc);
    if (c == 0) {
        int prev = -1; float cnt = 0.f;
        for (int r = r0; r < rend; ++r) {
            int b = batch[r];
            if (b != prev) {
                if (prev >= 0) atomicAdd(&gcnt[prev], cnt);
                prev = b; cnt = 0.f;
            }
            cnt += 1.f;
        }
        if (prev >= 0) atomicAdd(&gcnt[prev], cnt);
    }
}

__global__ void gmean_kernel(float* __restrict__ gsum,
                             const float* __restrict__ gcnt) {
    int i = blockIdx.x * blockDim.x + threadIdx.x;
    if (i >= NG * HIDC) return;
    gsum[i] = gsum[i] / fmaxf(gcnt[i >> 8], 1.f);
}

// ---------- gproj[b,c] = sum_k gmean[b,k] * Wq1[256+k, c]  (fp32) --------
__global__ __launch_bounds__(256)
void gproj_kernel(const float* __restrict__ gmean,
                  const float* __restrict__ Wq1, float* __restrict__ gproj) {
    int b = blockIdx.x, c = threadIdx.x;
    __shared__ float gm[HIDC];
    gm[c] = gmean[b * HIDC + c];
    __syncthreads();
    float acc = 0.f;
    for (int k = 0; k < HIDC; ++k)
        acc = fmaf(gm[k], Wq1[(long)(HIDC + k) * HIDC + c], acc);
    gproj[b * HIDC + c] = acc;
}

// ---------- head epilogue: hid = relu(hid + gproj[batch] + bq1), bf16 ----
__global__ void head_epilogue_kernel(u32* __restrict__ hid,
                                     const float* __restrict__ gproj,
                                     const int* __restrict__ batch,
                                     const float* __restrict__ bq1, int N) {
    int idx = blockIdx.x * 256 + threadIdx.x;
    if (idx >= N * (HIDC / 2)) return;
    int n = idx >> 7;
    int c0 = (idx & (HIDC / 2 - 1)) * 2;
    int b = batch[n];
    u32 v = hid[idx];
    float x0 = __uint_as_float(v << 16) + gproj[b * HIDC + c0] + bq1[c0];
    float x1 = __uint_as_float(v & 0xffff0000u) + gproj[b * HIDC + c0 + 1] + bq1[c0 + 1];
    x0 = x0 > 0.f ? x0 : 0.f;
    x1 = x1 > 0.f ? x1 : 0.f;
    hid[idx] = pack2(x0, x1);
}

// ---------- final q = hid @ Wq2 + bq2 (bf16 hid); batch as float ---------
__global__ __launch_bounds__(256)
void q_kernel(const u16* __restrict__ hid, const float* __restrict__ Wq2,
              const float* __restrict__ bq2, const int* __restrict__ batch,
              float* __restrict__ out, int N) {
    __shared__ float w[HIDC * 4];
    int t = threadIdx.x;
#pragma unroll
    for (int j = 0; j < 4; ++j) w[t + 256 * j] = Wq2[t + 256 * j];
    __syncthreads();
    int wid = t >> 6, lane = t & 63;
    int n = blockIdx.x * 4 + wid;
    if (n >= N) return;
    float a0 = 0, a1 = 0, a2 = 0, a3 = 0;
#pragma unroll
    for (int it = 0; it < 4; ++it) {
        int k = it * 64 + lane;
        float v = b2f(hid[(long)n * HIDC + k]);
        a0 = fmaf(v, w[k * 4 + 0], a0);
        a1 = fmaf(v, w[k * 4 + 1], a1);
        a2 = fmaf(v, w[k * 4 + 2], a2);
        a3 = fmaf(v, w[k * 4 + 3], a3);
    }
    for (int o = 32; o > 0; o >>= 1) {
        a0 += __shfl_down(a0, o, 64);
        a1 += __shfl_down(a1, o, 64);
        a2 += __shfl_down(a2, o, 64);
        a3 += __shfl_down(a3, o, 64);
    }
    if (lane == 0) {
        out[(long)n * 4 + 0] = a0 + bq2[0];
        out[(long)n * 4 + 1] = a1 + bq2[1];
        out[(long)n * 4 + 2] = a2 + bq2[2];
        out[(long)n * 4 + 3] = a3 + bq2[3];
        out[(long)N * 4 + n] = (float)batch[n];
    }
}

extern "C" void kernel_launch(void* const* d_in, const int* in_sizes, int n_in,
                              void* d_out, int out_size, void* d_ws, size_t ws_size,
                              hipStream_t stream) {
    const float* x   = (const float*)d_in[0];
    const int*   ei  = (const int*)d_in[1];
    const int*   bat = (const int*)d_in[2];
    const float* W1  = (const float*)d_in[3];
    const float* as1 = (const float*)d_in[4];
    const float* ad1 = (const float*)d_in[5];
    const float* g1  = (const float*)d_in[7];
    const float* be1 = (const float*)d_in[8];
    const float* W2  = (const float*)d_in[9];
    const float* as2 = (const float*)d_in[10];
    const float* ad2 = (const float*)d_in[11];
    const float* g2  = (const float*)d_in[13];
    const float* be2 = (const float*)d_in[14];
    const float* Wq1 = (const float*)d_in[15];
    const float* bq1 = (const float*)d_in[16];
    const float* Wq2 = (const float*)d_in[17];
    const float* bq2 = (const float*)d_in[18];
    float* out = (float*)d_out;

    const int N = in_sizes[0] / F_IN;   // 50000
    const int E = in_sizes[1] / 2;      // 800000
    const int Etot = E + N;
    const int nb = (N + 255) / 256;

    const size_t hbytes = (size_t)N * HIDC * sizeof(u16);   // 25.6 MB
    char* p = (char*)d_ws;
    u16* B1 = (u16*)p; p += hbytes;   // hb1, later hbn2
    u16* B2 = (u16*)p; p += hbytes;   // agg (both layers)
    u16* B3 = (u16*)p; p += hbytes;   // hbn1, later hid3
    u16* B4 = (u16*)p; p += hbytes;   // xb (bf16 x), later hb2
    u16* WT1 = (u16*)p; p += (size_t)HIDC * F_IN * sizeof(u16);
    u16* WT2 = (u16*)p; p += (size_t)HIDC * HIDC * sizeof(u16);
    u16* WQT = (u16*)p; p += (size_t)HIDC * HIDC * sizeof(u16);
    float* asrc   = (float*)p;  p += (size_t)N * 4 * 4;
    float* adst   = (float*)p;  p += (size_t)N * 4 * 4;
    int*   rowptr = (int*)p;    p += (size_t)(N + 1) * 4;
    int*   csr_src= (int*)p;    p += (size_t)Etot * 4;
    int*   cur    = (int*)p;    p += (size_t)N * 4;
    int*   part   = (int*)p;    p += (size_t)N * 4;
    int*   bsum   = (int*)p;    p += (size_t)nb * 4 + 64;
    float* bnsum  = (float*)p;  p += HIDC * 4;
    float* bnsq   = (float*)p;  p += HIDC * 4;
    float* gsum   = (float*)p;  p += NG * HIDC * 4;
    float* gcnt   = (float*)p;  p += NG * 4;
    float* gproj  = (float*)p;  p += NG * HIDC * 4;

    dim3 gemmGrid(2, (N / 16 + 3) / 4);     // 2 x 782 blocks, wave = 16x128
    int edgeBlocks = (Etot + 255) / 256;
    int nodeBlocksW = (N + 3) / 4;
    int halfElems = N * (HIDC / 2);

    // ===================== CSR build (once) ==============================
    hipMemsetAsync(cur, 0, (size_t)N * 4, stream);
    deg_kernel<<<edgeBlocks, 256, 0, stream>>>(ei, E, N, cur);
    scan_phase1<<<nb, 256, 0, stream>>>(cur, part, bsum, N);
    scan_phase2<<<1, 256, 0, stream>>>(bsum, nb);
    scan_phase3<<<nb, 256, 0, stream>>>(part, bsum, rowptr, N);
    hipMemsetAsync(cur, 0, (size_t)N * 4, stream);
    fill_kernel<<<edgeBlocks, 256, 0, stream>>>(ei, E, N, rowptr, cur, csr_src);

    // ===================== prep: bf16 conversions ========================
    f2b2_kernel<<<(N * F_IN / 2 + 255) / 256, 256, 0, stream>>>(x, (u32*)B4, N * F_IN / 2);
    wt_kernel<<<(F_IN * HIDC + 255) / 256, 256, 0, stream>>>(W1, WT1, F_IN, HIDC);
    wt_kernel<<<(HIDC * HIDC + 255) / 256, 256, 0, stream>>>(W2, WT2, HIDC, HIDC);
    wt_kernel<<<(HIDC * HIDC + 255) / 256, 256, 0, stream>>>(Wq1, WQT, HIDC, HIDC); // top 256 rows

    // ===================== Layer 1 (GAT 128 -> 4x64) =====================
    gemm_mfma_kernel<F_IN><<<gemmGrid, 256, 0, stream>>>(B4, WT1, B1, N);
    alpha_reduce_kernel<<<nodeBlocksW, 256, 0, stream>>>(B1, as1, ad1, asrc, adst, N, 4);
    gat_gather_kernel<4><<<nodeBlocksW, 256, 0, stream>>>(rowptr, csr_src, asrc, adst, B1, B2, N);
    hipMemsetAsync(bnsum, 0, HIDC * 4, stream);
    hipMemsetAsync(bnsq, 0, HIDC * 4, stream);
    bn_stats_kernel<<<(N + 127) / 128, 256, 0, stream>>>(B2, N, bnsum, bnsq);
    bn_apply_relu_kernel<<<(halfElems + 255) / 256, 256, 0, stream>>>((u32*)B2, (u32*)B3, N, bnsum, bnsq, g1, be1);

    // ===================== Layer 2 (GAT 256 -> 256, 1 head) ==============
    gemm_mfma_kernel<HIDC><<<gemmGrid, 256, 0, stream>>>(B3, WT2, B4, N);
    alpha_reduce_kernel<<<nodeBlocksW, 256, 0, stream>>>(B4, as2, ad2, asrc, adst, N, 1);
    gat_gather_kernel<1><<<nodeBlocksW, 256, 0, stream>>>(rowptr, csr_src, asrc, adst, B4, B2, N);
    hipMemsetAsync(bnsum, 0, HIDC * 4, stream);
    hipMemsetAsync(bnsq, 0, HIDC * 4, stream);
    bn_stats_kernel<<<(N + 127) / 128, 256, 0, stream>>>(B2, N, bnsum, bnsq);
    bn_apply_relu_kernel<<<(halfElems + 255) / 256, 256, 0, stream>>>((u32*)B2, (u32*)B1, N, bnsum, bnsq, g2, be2);

    // ===================== Pool + head ===================================
    hipMemsetAsync(gsum, 0, NG * HIDC * 4, stream);
    hipMemsetAsync(gcnt, 0, NG * 4, stream);
    pool_kernel<<<(N + 127) / 128, 256, 0, stream>>>(B1, bat, N, gsum, gcnt);
    gmean_kernel<<<(NG * HIDC + 255) / 256, 256, 0, stream>>>(gsum, gcnt);
    gproj_kernel<<<NG, 256, 0, stream>>>(gsum, Wq1, gproj);
    gemm_mfma_kernel<HIDC><<<gemmGrid, 256, 0, stream>>>(B1, WQT, B3, N);
    head_epilogue_kernel<<<(halfElems + 255) / 256, 256, 0, stream>>>((u32*)B3, gproj, bat, bq1, N);
    q_kernel<<<nodeBlocksW, 256, 0, stream>>>(B3, Wq2, bq2, bat, out, N);
}

// Round 5
// 651.907 us; speedup vs baseline: 10.2591x; 1.2361x over previous
//
#include <hip/hip_runtime.h>
#include <hip/hip_bf16.h>
#include <math.h>

#define F_IN  128
#define HIDC  256
#define NG    8
#define EPS_BN 1e-5f

typedef unsigned short u16;
typedef unsigned int   u32;
typedef __attribute__((ext_vector_type(8))) short bf16x8;
typedef __attribute__((ext_vector_type(4))) float f32x4;

// ---------- bf16 helpers ----------
static __device__ __forceinline__ float b2f(u16 u) {
    return __uint_as_float((u32)u << 16);
}
static __device__ __forceinline__ u16 f2b(float f) {   // RNE
    u32 u = __float_as_uint(f);
    u32 r = (u + 0x7fffu + ((u >> 16) & 1u)) >> 16;
    return (u16)r;
}
static __device__ __forceinline__ u32 pack2(float a, float b) {
    return (u32)f2b(a) | ((u32)f2b(b) << 16);
}
static __device__ __forceinline__ float lk(float v) {   // leaky relu 0.2
    return v >= 0.f ? v : 0.2f * v;
}

// ---------- prep: fp32 -> bf16 (paired) ----------
__global__ void f2b2_kernel(const float* __restrict__ in, u32* __restrict__ out, int npair) {
    int i = blockIdx.x * 256 + threadIdx.x;
    if (i >= npair) return;
    float2 v = ((const float2*)in)[i];
    out[i] = pack2(v.x, v.y);
}

// ---------- prep: W [K][Ncol] fp32 -> WT [Ncol][K] bf16 ----------
__global__ void wt_kernel(const float* __restrict__ W, u16* __restrict__ WT,
                          int K, int Ncol) {
    int i = blockIdx.x * 256 + threadIdx.x;
    if (i >= K * Ncol) return;
    int n = i / K, k = i % K;
    WT[i] = f2b(W[(long)k * Ncol + n]);
}

// ---------- BN coefficients: scale = g*rsqrt(var), bias = beta - mu*scale --
__global__ void bn_coef_kernel(const float* __restrict__ sum,
                               const float* __restrict__ sumsq,
                               const float* __restrict__ gamma,
                               const float* __restrict__ beta,
                               float* __restrict__ scale,
                               float* __restrict__ bias, int N) {
    int c = threadIdx.x;
    float invN = 1.f / (float)N;
    float mu = sum[c] * invN;
    float var = sumsq[c] * invN - mu * mu;
    float inv = rsqrtf(var + EPS_BN);
    float sc = gamma[c] * inv;
    scale[c] = sc;
    bias[c] = beta[c] - mu * sc;
}

// ---------- MFMA GEMM: C[M,256] = act(A)[M,K] @ WT^T, fused epilogues -----
// MODE 0: plain A;  epilogue stores C + H=4 alpha logits (direct store)
// MODE 1: BN+relu A; epilogue stores C + H=1 alpha logits (atomicAdd)
// MODE 2: BN+relu A; epilogue C = relu(acc + gproj[bat] + bq1)
template <int K, int MODE>
__global__ __launch_bounds__(256)
void gemm_mfma_kernel(const u16* __restrict__ A, const u16* __restrict__ WT,
                      u16* __restrict__ C, int M,
                      const float* __restrict__ scaleA, const float* __restrict__ biasA,
                      const float* __restrict__ wsrc, const float* __restrict__ wdst,
                      float* __restrict__ asrc, float* __restrict__ adst,
                      const float* __restrict__ gproj, const int* __restrict__ bat,
                      const float* __restrict__ bq1) {
    int wid = threadIdx.x >> 6, lane = threadIdx.x & 63;
    int m0 = (blockIdx.y * 4 + wid) * 16;
    if (m0 >= M) return;            // M % 16 == 0: waves fully in or out
    int n0 = blockIdx.x * 128;
    int row = lane & 15, quad = lane >> 4;
    const u16* Ap = A + (size_t)(m0 + row) * K + quad * 8;
    f32x4 acc[8];
#pragma unroll
    for (int t = 0; t < 8; ++t) acc[t] = (f32x4){0.f, 0.f, 0.f, 0.f};
#pragma unroll
    for (int k0 = 0; k0 < K; k0 += 32) {
        bf16x8 a = *(const bf16x8*)(Ap + k0);
        if constexpr (MODE != 0) {   // fused BN + relu on A fragment
            int c0 = k0 + quad * 8;
            float4 s0 = *(const float4*)(scaleA + c0);
            float4 s1 = *(const float4*)(scaleA + c0 + 4);
            float4 b0 = *(const float4*)(biasA + c0);
            float4 b1 = *(const float4*)(biasA + c0 + 4);
            float xv[8];
#pragma unroll
            for (int j = 0; j < 8; ++j) xv[j] = b2f((u16)a[j]);
            xv[0] = fmaxf(fmaf(s0.x, xv[0], b0.x), 0.f);
            xv[1] = fmaxf(fmaf(s0.y, xv[1], b0.y), 0.f);
            xv[2] = fmaxf(fmaf(s0.z, xv[2], b0.z), 0.f);
            xv[3] = fmaxf(fmaf(s0.w, xv[3], b0.w), 0.f);
            xv[4] = fmaxf(fmaf(s1.x, xv[4], b1.x), 0.f);
            xv[5] = fmaxf(fmaf(s1.y, xv[5], b1.y), 0.f);
            xv[6] = fmaxf(fmaf(s1.z, xv[6], b1.z), 0.f);
            xv[7] = fmaxf(fmaf(s1.w, xv[7], b1.w), 0.f);
#pragma unroll
            for (int j = 0; j < 8; ++j) a[j] = (short)f2b(xv[j]);
        }
#pragma unroll
        for (int t = 0; t < 8; ++t) {
            const u16* Bp = WT + (size_t)(n0 + t * 16 + row) * K + k0 + quad * 8;
            bf16x8 b = *(const bf16x8*)Bp;
            acc[t] = __builtin_amdgcn_mfma_f32_16x16x32_bf16(a, b, acc[t], 0, 0, 0);
        }
    }
    // C/D layout: col = lane&15 (row var), row-of-C = quad*4 + reg
    if constexpr (MODE == 2) {       // fused head epilogue
        int bm[4];
#pragma unroll
        for (int r = 0; r < 4; ++r) bm[r] = bat[m0 + quad * 4 + r];
#pragma unroll
        for (int t = 0; t < 8; ++t) {
            int n = n0 + t * 16 + row;
            float bq = bq1[n];
#pragma unroll
            for (int r = 0; r < 4; ++r) {
                float v = acc[t][r] + gproj[bm[r] * HIDC + n] + bq;
                C[(size_t)(m0 + quad * 4 + r) * HIDC + n] = f2b(fmaxf(v, 0.f));
            }
        }
    } else {
#pragma unroll
        for (int t = 0; t < 8; ++t) {
            int n = n0 + t * 16 + row;
#pragma unroll
            for (int r = 0; r < 4; ++r)
                C[(size_t)(m0 + quad * 4 + r) * HIDC + n] = f2b(acc[t][r]);
        }
        if constexpr (MODE == 0) {   // H=4 alpha logits; this block owns 2 heads
            float pa[2][4] = {}, pd[2][4] = {};
#pragma unroll
            for (int t = 0; t < 8; ++t) {
                float ws = wsrc[n0 + t * 16 + row];
                float wd = wdst[n0 + t * 16 + row];
                int hf = t >> 2;
#pragma unroll
                for (int r = 0; r < 4; ++r) {
                    pa[hf][r] = fmaf(acc[t][r], ws, pa[hf][r]);
                    pd[hf][r] = fmaf(acc[t][r], wd, pd[hf][r]);
                }
            }
#pragma unroll
            for (int off = 1; off < 16; off <<= 1)
#pragma unroll
                for (int hf = 0; hf < 2; ++hf)
#pragma unroll
                    for (int r = 0; r < 4; ++r) {
                        pa[hf][r] += __shfl_xor(pa[hf][r], off, 64);
                        pd[hf][r] += __shfl_xor(pd[hf][r], off, 64);
                    }
            if (row == 0) {
                int hbase = n0 >> 6;
#pragma unroll
                for (int r = 0; r < 4; ++r) {
                    int m = m0 + quad * 4 + r;
#pragma unroll
                    for (int hf = 0; hf < 2; ++hf) {
                        asrc[m * 4 + hbase + hf] = pa[hf][r];
                        adst[m * 4 + hbase + hf] = pd[hf][r];
                    }
                }
            }
        }
        if constexpr (MODE == 1) {   // H=1 alpha logits; 2 blocks sum via atomics
            float pa[4] = {}, pd[4] = {};
#pragma unroll
            for (int t = 0; t < 8; ++t) {
                float ws = wsrc[n0 + t * 16 + row];
                float wd = wdst[n0 + t * 16 + row];
#pragma unroll
                for (int r = 0; r < 4; ++r) {
                    pa[r] = fmaf(acc[t][r], ws, pa[r]);
                    pd[r] = fmaf(acc[t][r], wd, pd[r]);
                }
            }
#pragma unroll
            for (int off = 1; off < 16; off <<= 1)
#pragma unroll
                for (int r = 0; r < 4; ++r) {
                    pa[r] += __shfl_xor(pa[r], off, 64);
                    pd[r] += __shfl_xor(pd[r], off, 64);
                }
            if (row == 0) {
#pragma unroll
                for (int r = 0; r < 4; ++r) {
                    int m = m0 + quad * 4 + r;
                    atomicAdd(&asrc[m], pa[r]);
                    atomicAdd(&adst[m], pd[r]);
                }
            }
        }
    }
}

// =================== CSR build (by destination), built once ===============
__global__ void deg_kernel(const int* __restrict__ ei, int E, int N,
                           int* __restrict__ deg) {
    int e = blockIdx.x * blockDim.x + threadIdx.x;
    if (e >= E + N) return;
    int d = (e < E) ? ei[E + e] : (e - E);
    atomicAdd(&deg[d], 1);
}

__global__ __launch_bounds__(256)
void scan_phase1(const int* __restrict__ deg, int* __restrict__ part,
                 int* __restrict__ bsum, int N) {
    __shared__ int tmp[256];
    int i = blockIdx.x * 256 + threadIdx.x;
    int v = (i < N) ? deg[i] : 0;
    tmp[threadIdx.x] = v;
    __syncthreads();
    for (int off = 1; off < 256; off <<= 1) {
        int t = (threadIdx.x >= off) ? tmp[threadIdx.x - off] : 0;
        __syncthreads();
        tmp[threadIdx.x] += t;
        __syncthreads();
    }
    if (i < N) part[i] = tmp[threadIdx.x];
    if (threadIdx.x == 255) bsum[blockIdx.x] = tmp[255];
}
__global__ __launch_bounds__(256)
void scan_phase2(int* __restrict__ bsum, int nb) {
    __shared__ int tmp[256];
    int v = (threadIdx.x < nb) ? bsum[threadIdx.x] : 0;
    tmp[threadIdx.x] = v;
    __syncthreads();
    for (int off = 1; off < 256; off <<= 1) {
        int t = (threadIdx.x >= off) ? tmp[threadIdx.x - off] : 0;
        __syncthreads();
        tmp[threadIdx.x] += t;
        __syncthreads();
    }
    if (threadIdx.x < nb)
        bsum[threadIdx.x] = threadIdx.x ? tmp[threadIdx.x - 1] : 0;
}
__global__ __launch_bounds__(256)
void scan_phase3(const int* __restrict__ part, const int* __restrict__ bsum,
                 int* __restrict__ rowptr, int N) {
    int i = blockIdx.x * 256 + threadIdx.x;
    if (i < N) rowptr[i + 1] = part[i] + bsum[blockIdx.x];
    if (i == 0) rowptr[0] = 0;
}

__global__ void fill_kernel(const int* __restrict__ ei, int E, int N,
                            const int* __restrict__ rowptr,
                            int* __restrict__ cur, int* __restrict__ csr_src) {
    int e = blockIdx.x * blockDim.x + threadIdx.x;
    if (e >= E + N) return;
    int s = (e < E) ? ei[e] : (e - E);
    int d = (e < E) ? ei[E + e] : (e - E);
    int pos = rowptr[d] + atomicAdd(&cur[d], 1);
    csr_src[pos] = s;
}

// ========== fused GAT edge-softmax + aggregation (online softmax) =========
// wave per dst node; LDS staging for (src, alpha); 4x-unrolled accumulate.
template <int H>
__global__ __launch_bounds__(256)
void gat_gather_kernel(const int* __restrict__ rowptr,
                       const int* __restrict__ csr_src,
                       const float* __restrict__ asrc,
                       const float* __restrict__ adst,
                       const u16* __restrict__ h,
                       u16* __restrict__ agg, int N) {
    __shared__ __align__(16) float s_alpha[4][64 * H];
    __shared__ int s_src[4][64];
    int wid = threadIdx.x >> 6, lane = threadIdx.x & 63;
    int n = blockIdx.x * 4 + wid;
    if (n >= N) return;
    int start = rowptr[n], end = rowptr[n + 1];
    float ad[H];
#pragma unroll
    for (int hh = 0; hh < H; ++hh) ad[hh] = adst[n * H + hh];

    // single online-softmax pass: per-lane running (m, d) per head
    float m[H], d[H];
#pragma unroll
    for (int hh = 0; hh < H; ++hh) { m[hh] = -1e30f; d[hh] = 0.f; }
    for (int i = start + lane; i < end; i += 64) {
        int s = csr_src[i];
        float av[H];
        if (H == 4) {
            float4 a4 = *(const float4*)(asrc + s * 4);
            av[0] = a4.x; av[1 % H] = a4.y; av[2 % H] = a4.z; av[3 % H] = a4.w;
        } else {
            av[0] = asrc[s];
        }
#pragma unroll
        for (int hh = 0; hh < H; ++hh) {
            float v = lk(av[hh] + ad[hh]);
            float mn = fmaxf(m[hh], v);
            d[hh] = fmaf(d[hh], __expf(m[hh] - mn), __expf(v - mn));
            m[hh] = mn;
        }
    }
#pragma unroll
    for (int off = 1; off < 64; off <<= 1)
#pragma unroll
        for (int hh = 0; hh < H; ++hh) {
            float mo = __shfl_xor(m[hh], off, 64);
            float dd = __shfl_xor(d[hh], off, 64);
            float mn = fmaxf(m[hh], mo);
            d[hh] = d[hh] * __expf(m[hh] - mn) + dd * __expf(mo - mn);
            m[hh] = mn;
        }
    float invd[H];
#pragma unroll
    for (int hh = 0; hh < H; ++hh) invd[hh] = 1.f / (d[hh] + 1e-16f);

    // accumulate: lane owns channels [lane*4, lane*4+4)
    float acc0 = 0.f, acc1 = 0.f, acc2 = 0.f, acc3 = 0.f;
    const int head = (H == 4) ? (lane >> 4) : 0;
    const uint2* hp = (const uint2*)h;
    for (int base = start; base < end; base += 64) {
        int cnt = min(64, end - base);
        if (lane < cnt) {
            int s = csr_src[base + lane];
            s_src[wid][lane] = s;
            if (H == 4) {
                float4 a4 = *(const float4*)(asrc + s * 4);
                float4 av;
                av.x = __expf(lk(a4.x + ad[0]) - m[0]) * invd[0];
                av.y = __expf(lk(a4.y + ad[1 % H]) - m[1 % H]) * invd[1 % H];
                av.z = __expf(lk(a4.z + ad[2 % H]) - m[2 % H]) * invd[2 % H];
                av.w = __expf(lk(a4.w + ad[3 % H]) - m[3 % H]) * invd[3 % H];
                *(float4*)&s_alpha[wid][lane * 4] = av;
            } else {
                s_alpha[wid][lane] = __expf(lk(asrc[s] + ad[0]) - m[0]) * invd[0];
            }
        }
        // wave-synchronous LDS: DS ops from one wave complete in order
#define GBODY(J) { int s_ = s_src[wid][(J)];                                   \
            float al_ = s_alpha[wid][(H == 4) ? ((J) * 4 + head) : (J)];       \
            uint2 hv_ = hp[(u32)s_ * 64u + (u32)lane];                         \
            acc0 = fmaf(__uint_as_float(hv_.x << 16), al_, acc0);              \
            acc1 = fmaf(__uint_as_float(hv_.x & 0xffff0000u), al_, acc1);      \
            acc2 = fmaf(__uint_as_float(hv_.y << 16), al_, acc2);              \
            acc3 = fmaf(__uint_as_float(hv_.y & 0xffff0000u), al_, acc3); }
        int j = 0;
        for (; j + 4 <= cnt; j += 4) { GBODY(j) GBODY(j + 1) GBODY(j + 2) GBODY(j + 3) }
        for (; j < cnt; ++j) GBODY(j)
#undef GBODY
    }
    uint2 o;
    o.x = pack2(acc0, acc1);
    o.y = pack2(acc2, acc3);
    ((uint2*)(agg + (size_t)n * HIDC))[lane] = o;
}

// ---------- BatchNorm stats (bf16 in, fp32 accumulate) ----------
__global__ __launch_bounds__(256)
void bn_stats_kernel(const u16* __restrict__ h, int N,
                     float* __restrict__ sum, float* __restrict__ sumsq) {
    int c = threadIdx.x;
    int r0 = blockIdx.x * 128;
    int rend = min(r0 + 128, N);
    float s = 0.f, q = 0.f;
    for (int r = r0; r < rend; ++r) {
        float v = b2f(h[(long)r * HIDC + c]);
        s += v;
        q += v * v;
    }
    atomicAdd(&sum[c], s);
    atomicAdd(&sumsq[c], q);
}

// ---------- graph mean pooling with inline BN+relu (batch sorted) ---------
__global__ __launch_bounds__(256)
void pool_bn_kernel(const u16* __restrict__ h, const int* __restrict__ batch,
                    int N, const float* __restrict__ scale,
                    const float* __restrict__ bias,
                    float* __restrict__ gsum, float* __restrict__ gcnt) {
    int c = threadIdx.x;
    float sc = scale[c], bi = bias[c];
    int r0 = blockIdx.x * 128;
    int rend = min(r0 + 128, N);
    int curb = -1;
    float acc = 0.f;
    for (int r = r0; r < rend; ++r) {
        int b = batch[r];
        if (b != curb) {
            if (curb >= 0) atomicAdd(&gsum[curb * HIDC + c], acc);
            curb = b; acc = 0.f;
        }
        acc += fmaxf(fmaf(sc, b2f(h[(long)r * HIDC + c]), bi), 0.f);
    }
    if (curb >= 0) atomicAdd(&gsum[curb * HIDC + c], acc);
    if (c == 0) {
        int prev = -1; float cnt = 0.f;
        for (int r = r0; r < rend; ++r) {
            int b = batch[r];
            if (b != prev) {
                if (prev >= 0) atomicAdd(&gcnt[prev], cnt);
                prev = b; cnt = 0.f;
            }
            cnt += 1.f;
        }
        if (prev >= 0) atomicAdd(&gcnt[prev], cnt);
    }
}

// ---------- gmean + projection: gproj[b,c] = Σ_k gmean[b,k]*Wq1[256+k,c] --
__global__ __launch_bounds__(256)
void gmean_gproj_kernel(const float* __restrict__ gsum,
                        const float* __restrict__ gcnt,
                        const float* __restrict__ Wq1,
                        float* __restrict__ gproj) {
    int b = blockIdx.x, c = threadIdx.x;
    __shared__ float gm[HIDC];
    gm[c] = gsum[b * HIDC + c] / fmaxf(gcnt[b], 1.f);
    __syncthreads();
    float acc = 0.f;
    for (int k = 0; k < HIDC; ++k)
        acc = fmaf(gm[k], Wq1[(long)(HIDC + k) * HIDC + c], acc);
    gproj[b * HIDC + c] = acc;
}

// ---------- final q = hid @ Wq2 + bq2 (bf16 hid); batch as float ---------
__global__ __launch_bounds__(256)
void q_kernel(const u16* __restrict__ hid, const float* __restrict__ Wq2,
              const float* __restrict__ bq2, const int* __restrict__ batch,
              float* __restrict__ out, int N) {
    __shared__ float w[HIDC * 4];
    int t = threadIdx.x;
#pragma unroll
    for (int j = 0; j < 4; ++j) w[t + 256 * j] = Wq2[t + 256 * j];
    __syncthreads();
    int wid = t >> 6, lane = t & 63;
    int n = blockIdx.x * 4 + wid;
    if (n >= N) return;
    float a0 = 0, a1 = 0, a2 = 0, a3 = 0;
#pragma unroll
    for (int it = 0; it < 4; ++it) {
        int k = it * 64 + lane;
        float v = b2f(hid[(long)n * HIDC + k]);
        a0 = fmaf(v, w[k * 4 + 0], a0);
        a1 = fmaf(v, w[k * 4 + 1], a1);
        a2 = fmaf(v, w[k * 4 + 2], a2);
        a3 = fmaf(v, w[k * 4 + 3], a3);
    }
    for (int o = 32; o > 0; o >>= 1) {
        a0 += __shfl_down(a0, o, 64);
        a1 += __shfl_down(a1, o, 64);
        a2 += __shfl_down(a2, o, 64);
        a3 += __shfl_down(a3, o, 64);
    }
    if (lane == 0) {
        out[(long)n * 4 + 0] = a0 + bq2[0];
        out[(long)n * 4 + 1] = a1 + bq2[1];
        out[(long)n * 4 + 2] = a2 + bq2[2];
        out[(long)n * 4 + 3] = a3 + bq2[3];
        out[(long)N * 4 + n] = (float)batch[n];
    }
}

extern "C" void kernel_launch(void* const* d_in, const int* in_sizes, int n_in,
                              void* d_out, int out_size, void* d_ws, size_t ws_size,
                              hipStream_t stream) {
    const float* x   = (const float*)d_in[0];
    const int*   ei  = (const int*)d_in[1];
    const int*   bat = (const int*)d_in[2];
    const float* W1  = (const float*)d_in[3];
    const float* as1 = (const float*)d_in[4];
    const float* ad1 = (const float*)d_in[5];
    const float* g1  = (const float*)d_in[7];
    const float* be1 = (const float*)d_in[8];
    const float* W2  = (const float*)d_in[9];
    const float* as2 = (const float*)d_in[10];
    const float* ad2 = (const float*)d_in[11];
    const float* g2  = (const float*)d_in[13];
    const float* be2 = (const float*)d_in[14];
    const float* Wq1 = (const float*)d_in[15];
    const float* bq1 = (const float*)d_in[16];
    const float* Wq2 = (const float*)d_in[17];
    const float* bq2 = (const float*)d_in[18];
    float* out = (float*)d_out;

    const int N = in_sizes[0] / F_IN;   // 50000
    const int E = in_sizes[1] / 2;      // 800000
    const int Etot = E + N;
    const int nb = (N + 255) / 256;

    const size_t hbytes = (size_t)N * HIDC * sizeof(u16);   // 25.6 MB
    char* p = (char*)d_ws;
    auto alloc = [&](size_t sz) { char* q = p; p += (sz + 255) & ~(size_t)255; return q; };
    u16* BX   = (u16*)alloc((size_t)N * F_IN * sizeof(u16)); // bf16 x
    u16* BH   = (u16*)alloc(hbytes);   // h1 -> h2 -> hid3
    u16* BA   = (u16*)alloc(hbytes);   // agg1 -> agg2
    u16* WT1  = (u16*)alloc((size_t)HIDC * F_IN * sizeof(u16));
    u16* WT2  = (u16*)alloc((size_t)HIDC * HIDC * sizeof(u16));
    u16* WQT  = (u16*)alloc((size_t)HIDC * HIDC * sizeof(u16));
    // pairs sharing one memset are single allocations (alloc rounds to 256B!)
    float* asrc = (float*)alloc((size_t)N * 4 * 4 * 2);      // asrc | adst
    float* adst = asrc + (size_t)N * 4;
    int* rowptr  = (int*)alloc((size_t)(N + 1) * 4);
    int* csr_src = (int*)alloc((size_t)Etot * 4);
    int* cur     = (int*)alloc((size_t)N * 4 * 2);           // deg | fill cursor
    int* cur2    = cur + N;
    int* part    = (int*)alloc((size_t)N * 4);
    int* bsum    = (int*)alloc((size_t)nb * 4);
    float* bnsum = (float*)alloc(HIDC * 4 * 2);              // bnsum | bnsq
    float* bnsq  = bnsum + HIDC;
    float* sc1   = (float*)alloc(HIDC * 4);
    float* bi1   = (float*)alloc(HIDC * 4);
    float* sc2   = (float*)alloc(HIDC * 4);
    float* bi2   = (float*)alloc(HIDC * 4);
    float* gsum  = (float*)alloc((NG * HIDC + NG) * 4);      // gsum | gcnt
    float* gcnt  = gsum + NG * HIDC;
    float* gproj = (float*)alloc(NG * HIDC * 4);

    dim3 gemmGrid(2, (N / 16 + 3) / 4);
    int edgeBlocks = (Etot + 255) / 256;
    int nodeBlocksW = (N + 3) / 4;

    // ===================== CSR build (once) ==============================
    hipMemsetAsync(cur, 0, (size_t)N * 4 * 2, stream);        // cur + cur2
    deg_kernel<<<edgeBlocks, 256, 0, stream>>>(ei, E, N, cur);
    scan_phase1<<<nb, 256, 0, stream>>>(cur, part, bsum, N);
    scan_phase2<<<1, 256, 0, stream>>>(bsum, nb);
    scan_phase3<<<nb, 256, 0, stream>>>(part, bsum, rowptr, N);
    fill_kernel<<<edgeBlocks, 256, 0, stream>>>(ei, E, N, rowptr, cur2, csr_src);

    // ===================== prep: bf16 conversions ========================
    f2b2_kernel<<<(N * F_IN / 2 + 255) / 256, 256, 0, stream>>>(x, (u32*)BX, N * F_IN / 2);
    wt_kernel<<<(F_IN * HIDC + 255) / 256, 256, 0, stream>>>(W1, WT1, F_IN, HIDC);
    wt_kernel<<<(HIDC * HIDC + 255) / 256, 256, 0, stream>>>(W2, WT2, HIDC, HIDC);
    wt_kernel<<<(HIDC * HIDC + 255) / 256, 256, 0, stream>>>(Wq1, WQT, HIDC, HIDC);

    // ===================== Layer 1: GEMM(+alpha4) -> gather -> BN stats ==
    gemm_mfma_kernel<F_IN, 0><<<gemmGrid, 256, 0, stream>>>(
        BX, WT1, BH, N, nullptr, nullptr, as1, ad1, asrc, adst, nullptr, nullptr, nullptr);
    gat_gather_kernel<4><<<nodeBlocksW, 256, 0, stream>>>(rowptr, csr_src, asrc, adst, BH, BA, N);
    hipMemsetAsync(bnsum, 0, HIDC * 4 * 2, stream);           // bnsum + bnsq
    bn_stats_kernel<<<(N + 127) / 128, 256, 0, stream>>>(BA, N, bnsum, bnsq);
    bn_coef_kernel<<<1, HIDC, 0, stream>>>(bnsum, bnsq, g1, be1, sc1, bi1, N);

    // ===================== Layer 2: GEMM(BN-A, +alpha1) -> gather -> BN ==
    hipMemsetAsync(asrc, 0, (size_t)N * 4 * 4 * 2, stream);   // asrc + adst
    gemm_mfma_kernel<HIDC, 1><<<gemmGrid, 256, 0, stream>>>(
        BA, WT2, BH, N, sc1, bi1, as2, ad2, asrc, adst, nullptr, nullptr, nullptr);
    gat_gather_kernel<1><<<nodeBlocksW, 256, 0, stream>>>(rowptr, csr_src, asrc, adst, BH, BA, N);
    hipMemsetAsync(bnsum, 0, HIDC * 4 * 2, stream);
    bn_stats_kernel<<<(N + 127) / 128, 256, 0, stream>>>(BA, N, bnsum, bnsq);
    bn_coef_kernel<<<1, HIDC, 0, stream>>>(bnsum, bnsq, g2, be2, sc2, bi2, N);

    // ===================== Pool (BN inline) + projection =================
    hipMemsetAsync(gsum, 0, (NG * HIDC + NG) * 4, stream);    // gsum + gcnt
    pool_bn_kernel<<<(N + 127) / 128, 256, 0, stream>>>(BA, bat, N, sc2, bi2, gsum, gcnt);
    gmean_gproj_kernel<<<NG, HIDC, 0, stream>>>(gsum, gcnt, Wq1, gproj);

    // ===================== Head: GEMM(BN-A, fused epilogue) -> q =========
    gemm_mfma_kernel<HIDC, 2><<<gemmGrid, 256, 0, stream>>>(
        BA, WQT, BH, N, sc2, bi2, nullptr, nullptr, nullptr, nullptr, gproj, bat, bq1);
    q_kernel<<<nodeBlocksW, 256, 0, stream>>>(BH, Wq2, bq2, bat, out, N);
}

// Round 6
// 552.549 us; speedup vs baseline: 12.1039x; 1.1798x over previous
//
#include <hip/hip_runtime.h>
#include <hip/hip_bf16.h>
#include <math.h>

#define F_IN  128
#define HIDC  256
#define NG    8
#define EPS_BN 1e-5f

typedef unsigned short u16;
typedef unsigned int   u32;
typedef __attribute__((ext_vector_type(8))) short bf16x8;
typedef __attribute__((ext_vector_type(4))) float f32x4;

// ---------- bf16 helpers ----------
static __device__ __forceinline__ float b2f(u16 u) {
    return __uint_as_float((u32)u << 16);
}
static __device__ __forceinline__ u16 f2b(float f) {   // RNE
    u32 u = __float_as_uint(f);
    u32 r = (u + 0x7fffu + ((u >> 16) & 1u)) >> 16;
    return (u16)r;
}
static __device__ __forceinline__ u32 pack2(float a, float b) {
    return (u32)f2b(a) | ((u32)f2b(b) << 16);
}
static __device__ __forceinline__ float lk(float v) {   // leaky relu 0.2
    return v >= 0.f ? v : 0.2f * v;
}

// ---------- prep: fp32 -> bf16 (paired) ----------
__global__ void f2b2_kernel(const float* __restrict__ in, u32* __restrict__ out, int npair) {
    int i = blockIdx.x * 256 + threadIdx.x;
    if (i >= npair) return;
    float2 v = ((const float2*)in)[i];
    out[i] = pack2(v.x, v.y);
}

// ---------- prep: W [K][Ncol] fp32 -> WT [Ncol][K] bf16 ----------
__global__ void wt_kernel(const float* __restrict__ W, u16* __restrict__ WT,
                          int K, int Ncol) {
    int i = blockIdx.x * 256 + threadIdx.x;
    if (i >= K * Ncol) return;
    int n = i / K, k = i % K;
    WT[i] = f2b(W[(long)k * Ncol + n]);
}

// ---------- BN coefficients: scale = g*rsqrt(var), bias = beta - mu*scale --
__global__ void bn_coef_kernel(const float* __restrict__ sum,
                               const float* __restrict__ sumsq,
                               const float* __restrict__ gamma,
                               const float* __restrict__ beta,
                               float* __restrict__ scale,
                               float* __restrict__ bias, int N) {
    int c = threadIdx.x;
    float invN = 1.f / (float)N;
    float mu = sum[c] * invN;
    float var = sumsq[c] * invN - mu * mu;
    float inv = rsqrtf(var + EPS_BN);
    float sc = gamma[c] * inv;
    scale[c] = sc;
    bias[c] = beta[c] - mu * sc;
}

// ---------- MFMA GEMM: C[M,256] = act(A)[M,K] @ WT^T, LDS-staged B --------
// Block: 256 thr, stages WT strip [n0..n0+128) x K into LDS (row pad +8 u16
// -> even bank spread). Wave computes 32 rows x 128 cols: 2 A-fragments
// share every B ds_read. MODE 0: plain A, +H=4 alpha logits. MODE 1:
// BN+relu A, +H=1 alpha logits (atomicAdd). MODE 2: BN+relu A, head epilogue.
template <int K, int MODE>
__global__ __launch_bounds__(256)
void gemm_mfma_kernel(const u16* __restrict__ A, const u16* __restrict__ WT,
                      u16* __restrict__ C, int M,
                      const float* __restrict__ scaleA, const float* __restrict__ biasA,
                      const float* __restrict__ wsrc, const float* __restrict__ wdst,
                      float* __restrict__ asrc, float* __restrict__ adst,
                      const float* __restrict__ gproj, const int* __restrict__ bat,
                      const float* __restrict__ bq1) {
    __shared__ u16 sB[128][K + 8];
    int tid = threadIdx.x;
    int n0 = blockIdx.x * 128;

    // stage WT strip: 128 rows x K u16, coalesced 16B chunks
    constexpr int ROWCH = K * 2 / 16;          // uint4 per row
    const uint4* src = (const uint4*)(WT + (size_t)n0 * K);
    for (int i = tid; i < 128 * ROWCH; i += 256) {
        int r = i / ROWCH, c = i % ROWCH;
        *(uint4*)&sB[r][c * 8] = src[i];
    }
    __syncthreads();

    int wid = tid >> 6, lane = tid & 63;
    int row = lane & 15, quad = lane >> 4;     // row = C-col lane, quad*4+r = C-row
    int m0 = blockIdx.y * 128 + wid * 32;
    int mf0 = m0, mf1 = m0 + 16;               // M % 16 == 0: all-or-nothing
    bool v0 = mf0 < M, v1 = mf1 < M;
    if (!v0) return;                            // after barrier: safe
    const u16* Ap0 = A + (size_t)(mf0 + row) * K + quad * 8;
    const u16* Ap1 = A + (size_t)((v1 ? mf1 : mf0) + row) * K + quad * 8;

    f32x4 acc[2][8];
#pragma unroll
    for (int f = 0; f < 2; ++f)
#pragma unroll
        for (int t = 0; t < 8; ++t) acc[f][t] = (f32x4){0.f, 0.f, 0.f, 0.f};

#pragma unroll
    for (int k0 = 0; k0 < K; k0 += 32) {
        bf16x8 a[2];
        a[0] = *(const bf16x8*)(Ap0 + k0);
        a[1] = *(const bf16x8*)(Ap1 + k0);
        if constexpr (MODE != 0) {   // fused BN + relu on A fragments
            int c0 = k0 + quad * 8;
            float4 s0 = *(const float4*)(scaleA + c0);
            float4 s1 = *(const float4*)(scaleA + c0 + 4);
            float4 b0 = *(const float4*)(biasA + c0);
            float4 b1 = *(const float4*)(biasA + c0 + 4);
#pragma unroll
            for (int f = 0; f < 2; ++f) {
                float xv[8];
#pragma unroll
                for (int j = 0; j < 8; ++j) xv[j] = b2f((u16)a[f][j]);
                xv[0] = fmaxf(fmaf(s0.x, xv[0], b0.x), 0.f);
                xv[1] = fmaxf(fmaf(s0.y, xv[1], b0.y), 0.f);
                xv[2] = fmaxf(fmaf(s0.z, xv[2], b0.z), 0.f);
                xv[3] = fmaxf(fmaf(s0.w, xv[3], b0.w), 0.f);
                xv[4] = fmaxf(fmaf(s1.x, xv[4], b1.x), 0.f);
                xv[5] = fmaxf(fmaf(s1.y, xv[5], b1.y), 0.f);
                xv[6] = fmaxf(fmaf(s1.z, xv[6], b1.z), 0.f);
                xv[7] = fmaxf(fmaf(s1.w, xv[7], b1.w), 0.f);
#pragma unroll
                for (int j = 0; j < 8; ++j) a[f][j] = (short)f2b(xv[j]);
            }
        }
#pragma unroll
        for (int t = 0; t < 8; ++t) {
            bf16x8 b = *(const bf16x8*)&sB[t * 16 + row][k0 + quad * 8];
            acc[0][t] = __builtin_amdgcn_mfma_f32_16x16x32_bf16(a[0], b, acc[0][t], 0, 0, 0);
            acc[1][t] = __builtin_amdgcn_mfma_f32_16x16x32_bf16(a[1], b, acc[1][t], 0, 0, 0);
        }
    }

    int mf[2] = {mf0, mf1};
    bool vf[2] = {v0, v1};
    if constexpr (MODE == 2) {       // fused head epilogue
#pragma unroll
        for (int f = 0; f < 2; ++f) {
            if (!vf[f]) continue;
            int bm[4];
#pragma unroll
            for (int r = 0; r < 4; ++r) bm[r] = bat[mf[f] + quad * 4 + r];
#pragma unroll
            for (int t = 0; t < 8; ++t) {
                int n = n0 + t * 16 + row;
                float bq = bq1[n];
#pragma unroll
                for (int r = 0; r < 4; ++r) {
                    float v = acc[f][t][r] + gproj[bm[r] * HIDC + n] + bq;
                    C[(size_t)(mf[f] + quad * 4 + r) * HIDC + n] = f2b(fmaxf(v, 0.f));
                }
            }
        }
    } else {
#pragma unroll
        for (int f = 0; f < 2; ++f) {
            if (!vf[f]) continue;
#pragma unroll
            for (int t = 0; t < 8; ++t) {
                int n = n0 + t * 16 + row;
#pragma unroll
                for (int r = 0; r < 4; ++r)
                    C[(size_t)(mf[f] + quad * 4 + r) * HIDC + n] = f2b(acc[f][t][r]);
            }
        }
        if constexpr (MODE == 0) {   // H=4 alpha logits; block owns 2 heads
            float pa[2][2][4] = {}, pd[2][2][4] = {};
#pragma unroll
            for (int t = 0; t < 8; ++t) {
                float ws = wsrc[n0 + t * 16 + row];
                float wd = wdst[n0 + t * 16 + row];
                int hf = t >> 2;
#pragma unroll
                for (int f = 0; f < 2; ++f)
#pragma unroll
                    for (int r = 0; r < 4; ++r) {
                        pa[f][hf][r] = fmaf(acc[f][t][r], ws, pa[f][hf][r]);
                        pd[f][hf][r] = fmaf(acc[f][t][r], wd, pd[f][hf][r]);
                    }
            }
#pragma unroll
            for (int off = 1; off < 16; off <<= 1)
#pragma unroll
                for (int f = 0; f < 2; ++f)
#pragma unroll
                    for (int hf = 0; hf < 2; ++hf)
#pragma unroll
                        for (int r = 0; r < 4; ++r) {
                            pa[f][hf][r] += __shfl_xor(pa[f][hf][r], off, 64);
                            pd[f][hf][r] += __shfl_xor(pd[f][hf][r], off, 64);
                        }
            if (row == 0) {
                int hbase = n0 >> 6;
#pragma unroll
                for (int f = 0; f < 2; ++f) {
                    if (!vf[f]) continue;
#pragma unroll
                    for (int r = 0; r < 4; ++r) {
                        int m = mf[f] + quad * 4 + r;
#pragma unroll
                        for (int hf = 0; hf < 2; ++hf) {
                            asrc[m * 4 + hbase + hf] = pa[f][hf][r];
                            adst[m * 4 + hbase + hf] = pd[f][hf][r];
                        }
                    }
                }
            }
        }
        if constexpr (MODE == 1) {   // H=1 alpha logits; 2 blocks sum via atomics
            float pa[2][4] = {}, pd[2][4] = {};
#pragma unroll
            for (int t = 0; t < 8; ++t) {
                float ws = wsrc[n0 + t * 16 + row];
                float wd = wdst[n0 + t * 16 + row];
#pragma unroll
                for (int f = 0; f < 2; ++f)
#pragma unroll
                    for (int r = 0; r < 4; ++r) {
                        pa[f][r] = fmaf(acc[f][t][r], ws, pa[f][r]);
                        pd[f][r] = fmaf(acc[f][t][r], wd, pd[f][r]);
                    }
            }
#pragma unroll
            for (int off = 1; off < 16; off <<= 1)
#pragma unroll
                for (int f = 0; f < 2; ++f)
#pragma unroll
                    for (int r = 0; r < 4; ++r) {
                        pa[f][r] += __shfl_xor(pa[f][r], off, 64);
                        pd[f][r] += __shfl_xor(pd[f][r], off, 64);
                    }
            if (row == 0) {
#pragma unroll
                for (int f = 0; f < 2; ++f) {
                    if (!vf[f]) continue;
#pragma unroll
                    for (int r = 0; r < 4; ++r) {
                        int m = mf[f] + quad * 4 + r;
                        atomicAdd(&asrc[m], pa[f][r]);
                        atomicAdd(&adst[m], pd[f][r]);
                    }
                }
            }
        }
    }
}

// =================== CSR build (by destination), built once ===============
__global__ void deg_kernel(const int* __restrict__ ei, int E, int N,
                           int* __restrict__ deg) {
    int e = blockIdx.x * blockDim.x + threadIdx.x;
    if (e >= E + N) return;
    int d = (e < E) ? ei[E + e] : (e - E);
    atomicAdd(&deg[d], 1);
}

__global__ __launch_bounds__(256)
void scan_phase1(const int* __restrict__ deg, int* __restrict__ part,
                 int* __restrict__ bsum, int N) {
    __shared__ int tmp[256];
    int i = blockIdx.x * 256 + threadIdx.x;
    int v = (i < N) ? deg[i] : 0;
    tmp[threadIdx.x] = v;
    __syncthreads();
    for (int off = 1; off < 256; off <<= 1) {
        int t = (threadIdx.x >= off) ? tmp[threadIdx.x - off] : 0;
        __syncthreads();
        tmp[threadIdx.x] += t;
        __syncthreads();
    }
    if (i < N) part[i] = tmp[threadIdx.x];
    if (threadIdx.x == 255) bsum[blockIdx.x] = tmp[255];
}
__global__ __launch_bounds__(256)
void scan_phase2(int* __restrict__ bsum, int nb) {
    __shared__ int tmp[256];
    int v = (threadIdx.x < nb) ? bsum[threadIdx.x] : 0;
    tmp[threadIdx.x] = v;
    __syncthreads();
    for (int off = 1; off < 256; off <<= 1) {
        int t = (threadIdx.x >= off) ? tmp[threadIdx.x - off] : 0;
        __syncthreads();
        tmp[threadIdx.x] += t;
        __syncthreads();
    }
    if (threadIdx.x < nb)
        bsum[threadIdx.x] = threadIdx.x ? tmp[threadIdx.x - 1] : 0;
}
__global__ __launch_bounds__(256)
void scan_phase3(const int* __restrict__ part, const int* __restrict__ bsum,
                 int* __restrict__ rowptr, int N) {
    int i = blockIdx.x * 256 + threadIdx.x;
    if (i < N) rowptr[i + 1] = part[i] + bsum[blockIdx.x];
    if (i == 0) rowptr[0] = 0;
}

__global__ void fill_kernel(const int* __restrict__ ei, int E, int N,
                            const int* __restrict__ rowptr,
                            int* __restrict__ cur, int* __restrict__ csr_src) {
    int e = blockIdx.x * blockDim.x + threadIdx.x;
    if (e >= E + N) return;
    int s = (e < E) ? ei[e] : (e - E);
    int d = (e < E) ? ei[E + e] : (e - E);
    int pos = rowptr[d] + atomicAdd(&cur[d], 1);
    csr_src[pos] = s;
}

// ========== fused GAT edge-softmax + aggregation (online softmax) =========
// wave per dst node; LDS staging for (src, alpha); 4x-unrolled accumulate.
template <int H>
__global__ __launch_bounds__(256)
void gat_gather_kernel(const int* __restrict__ rowptr,
                       const int* __restrict__ csr_src,
                       const float* __restrict__ asrc,
                       const float* __restrict__ adst,
                       const u16* __restrict__ h,
                       u16* __restrict__ agg, int N) {
    __shared__ __align__(16) float s_alpha[4][64 * H];
    __shared__ int s_src[4][64];
    int wid = threadIdx.x >> 6, lane = threadIdx.x & 63;
    int n = blockIdx.x * 4 + wid;
    if (n >= N) return;
    int start = rowptr[n], end = rowptr[n + 1];
    float ad[H];
#pragma unroll
    for (int hh = 0; hh < H; ++hh) ad[hh] = adst[n * H + hh];

    // single online-softmax pass: per-lane running (m, d) per head
    float m[H], d[H];
#pragma unroll
    for (int hh = 0; hh < H; ++hh) { m[hh] = -1e30f; d[hh] = 0.f; }
    for (int i = start + lane; i < end; i += 64) {
        int s = csr_src[i];
        float av[H];
        if (H == 4) {
            float4 a4 = *(const float4*)(asrc + s * 4);
            av[0] = a4.x; av[1 % H] = a4.y; av[2 % H] = a4.z; av[3 % H] = a4.w;
        } else {
            av[0] = asrc[s];
        }
#pragma unroll
        for (int hh = 0; hh < H; ++hh) {
            float v = lk(av[hh] + ad[hh]);
            float mn = fmaxf(m[hh], v);
            d[hh] = fmaf(d[hh], __expf(m[hh] - mn), __expf(v - mn));
            m[hh] = mn;
        }
    }
#pragma unroll
    for (int off = 1; off < 64; off <<= 1)
#pragma unroll
        for (int hh = 0; hh < H; ++hh) {
            float mo = __shfl_xor(m[hh], off, 64);
            float dd = __shfl_xor(d[hh], off, 64);
            float mn = fmaxf(m[hh], mo);
            d[hh] = d[hh] * __expf(m[hh] - mn) + dd * __expf(mo - mn);
            m[hh] = mn;
        }
    float invd[H];
#pragma unroll
    for (int hh = 0; hh < H; ++hh) invd[hh] = 1.f / (d[hh] + 1e-16f);

    // accumulate: lane owns channels [lane*4, lane*4+4)
    float acc0 = 0.f, acc1 = 0.f, acc2 = 0.f, acc3 = 0.f;
    const int head = (H == 4) ? (lane >> 4) : 0;
    const uint2* hp = (const uint2*)h;
    for (int base = start; base < end; base += 64) {
        int cnt = min(64, end - base);
        if (lane < cnt) {
            int s = csr_src[base + lane];
            s_src[wid][lane] = s;
            if (H == 4) {
                float4 a4 = *(const float4*)(asrc + s * 4);
                float4 av;
                av.x = __expf(lk(a4.x + ad[0]) - m[0]) * invd[0];
                av.y = __expf(lk(a4.y + ad[1 % H]) - m[1 % H]) * invd[1 % H];
                av.z = __expf(lk(a4.z + ad[2 % H]) - m[2 % H]) * invd[2 % H];
                av.w = __expf(lk(a4.w + ad[3 % H]) - m[3 % H]) * invd[3 % H];
                *(float4*)&s_alpha[wid][lane * 4] = av;
            } else {
                s_alpha[wid][lane] = __expf(lk(asrc[s] + ad[0]) - m[0]) * invd[0];
            }
        }
        // wave-synchronous LDS: DS ops from one wave complete in order
#define GBODY(J) { int s_ = s_src[wid][(J)];                                   \
            float al_ = s_alpha[wid][(H == 4) ? ((J) * 4 + head) : (J)];       \
            uint2 hv_ = hp[(u32)s_ * 64u + (u32)lane];                         \
            acc0 = fmaf(__uint_as_float(hv_.x << 16), al_, acc0);              \
            acc1 = fmaf(__uint_as_float(hv_.x & 0xffff0000u), al_, acc1);      \
            acc2 = fmaf(__uint_as_float(hv_.y << 16), al_, acc2);              \
            acc3 = fmaf(__uint_as_float(hv_.y & 0xffff0000u), al_, acc3); }
        int j = 0;
        for (; j + 4 <= cnt; j += 4) { GBODY(j) GBODY(j + 1) GBODY(j + 2) GBODY(j + 3) }
        for (; j < cnt; ++j) GBODY(j)
#undef GBODY
    }
    uint2 o;
    o.x = pack2(acc0, acc1);
    o.y = pack2(acc2, acc3);
    ((uint2*)(agg + (size_t)n * HIDC))[lane] = o;
}

// ---------- BatchNorm stats (bf16 in, fp32 accumulate) ----------
__global__ __launch_bounds__(256)
void bn_stats_kernel(const u16* __restrict__ h, int N,
                     float* __restrict__ sum, float* __restrict__ sumsq) {
    int c = threadIdx.x;
    int r0 = blockIdx.x * 128;
    int rend = min(r0 + 128, N);
    float s = 0.f, q = 0.f;
    for (int r = r0; r < rend; ++r) {
        float v = b2f(h[(long)r * HIDC + c]);
        s += v;
        q += v * v;
    }
    atomicAdd(&sum[c], s);
    atomicAdd(&sumsq[c], q);
}

// ---------- graph mean pooling with inline BN+relu (batch sorted) ---------
__global__ __launch_bounds__(256)
void pool_bn_kernel(const u16* __restrict__ h, const int* __restrict__ batch,
                    int N, const float* __restrict__ scale,
                    const float* __restrict__ bias,
                    float* __restrict__ gsum, float* __restrict__ gcnt) {
    int c = threadIdx.x;
    float sc = scale[c], bi = bias[c];
    int r0 = blockIdx.x * 128;
    int rend = min(r0 + 128, N);
    int curb = -1;
    float acc = 0.f;
    for (int r = r0; r < rend; ++r) {
        int b = batch[r];
        if (b != curb) {
            if (curb >= 0) atomicAdd(&gsum[curb * HIDC + c], acc);
            curb = b; acc = 0.f;
        }
        acc += fmaxf(fmaf(sc, b2f(h[(long)r * HIDC + c]), bi), 0.f);
    }
    if (curb >= 0) atomicAdd(&gsum[curb * HIDC + c], acc);
    if (c == 0) {
        int prev = -1; float cnt = 0.f;
        for (int r = r0; r < rend; ++r) {
            int b = batch[r];
            if (b != prev) {
                if (prev >= 0) atomicAdd(&gcnt[prev], cnt);
                prev = b; cnt = 0.f;
            }
            cnt += 1.f;
        }
        if (prev >= 0) atomicAdd(&gcnt[prev], cnt);
    }
}

// ---------- gmean + projection: gproj[b,c] = Σ_k gmean[b,k]*Wq1[256+k,c] --
__global__ __launch_bounds__(256)
void gmean_gproj_kernel(const float* __restrict__ gsum,
                        const float* __restrict__ gcnt,
                        const float* __restrict__ Wq1,
                        float* __restrict__ gproj) {
    int b = blockIdx.x, c = threadIdx.x;
    __shared__ float gm[HIDC];
    gm[c] = gsum[b * HIDC + c] / fmaxf(gcnt[b], 1.f);
    __syncthreads();
    float acc = 0.f;
    for (int k = 0; k < HIDC; ++k)
        acc = fmaf(gm[k], Wq1[(long)(HIDC + k) * HIDC + c], acc);
    gproj[b * HIDC + c] = acc;
}

// ---------- final q = hid @ Wq2 + bq2 (bf16 hid); batch as float ---------
__global__ __launch_bounds__(256)
void q_kernel(const u16* __restrict__ hid, const float* __restrict__ Wq2,
              const float* __restrict__ bq2, const int* __restrict__ batch,
              float* __restrict__ out, int N) {
    __shared__ float w[HIDC * 4];
    int t = threadIdx.x;
#pragma unroll
    for (int j = 0; j < 4; ++j) w[t + 256 * j] = Wq2[t + 256 * j];
    __syncthreads();
    int wid = t >> 6, lane = t & 63;
    int n = blockIdx.x * 4 + wid;
    if (n >= N) return;
    float a0 = 0, a1 = 0, a2 = 0, a3 = 0;
#pragma unroll
    for (int it = 0; it < 4; ++it) {
        int k = it * 64 + lane;
        float v = b2f(hid[(long)n * HIDC + k]);
        a0 = fmaf(v, w[k * 4 + 0], a0);
        a1 = fmaf(v, w[k * 4 + 1], a1);
        a2 = fmaf(v, w[k * 4 + 2], a2);
        a3 = fmaf(v, w[k * 4 + 3], a3);
    }
    for (int o = 32; o > 0; o >>= 1) {
        a0 += __shfl_down(a0, o, 64);
        a1 += __shfl_down(a1, o, 64);
        a2 += __shfl_down(a2, o, 64);
        a3 += __shfl_down(a3, o, 64);
    }
    if (lane == 0) {
        out[(long)n * 4 + 0] = a0 + bq2[0];
        out[(long)n * 4 + 1] = a1 + bq2[1];
        out[(long)n * 4 + 2] = a2 + bq2[2];
        out[(long)n * 4 + 3] = a3 + bq2[3];
        out[(long)N * 4 + n] = (float)batch[n];
    }
}

extern "C" void kernel_launch(void* const* d_in, const int* in_sizes, int n_in,
                              void* d_out, int out_size, void* d_ws, size_t ws_size,
                              hipStream_t stream) {
    const float* x   = (const float*)d_in[0];
    const int*   ei  = (const int*)d_in[1];
    const int*   bat = (const int*)d_in[2];
    const float* W1  = (const float*)d_in[3];
    const float* as1 = (const float*)d_in[4];
    const float* ad1 = (const float*)d_in[5];
    const float* g1  = (const float*)d_in[7];
    const float* be1 = (const float*)d_in[8];
    const float* W2  = (const float*)d_in[9];
    const float* as2 = (const float*)d_in[10];
    const float* ad2 = (const float*)d_in[11];
    const float* g2  = (const float*)d_in[13];
    const float* be2 = (const float*)d_in[14];
    const float* Wq1 = (const float*)d_in[15];
    const float* bq1 = (const float*)d_in[16];
    const float* Wq2 = (const float*)d_in[17];
    const float* bq2 = (const float*)d_in[18];
    float* out = (float*)d_out;

    const int N = in_sizes[0] / F_IN;   // 50000
    const int E = in_sizes[1] / 2;      // 800000
    const int Etot = E + N;
    const int nb = (N + 255) / 256;

    const size_t hbytes = (size_t)N * HIDC * sizeof(u16);   // 25.6 MB
    char* p = (char*)d_ws;
    auto alloc = [&](size_t sz) { char* q = p; p += (sz + 255) & ~(size_t)255; return q; };
    u16* BX   = (u16*)alloc((size_t)N * F_IN * sizeof(u16)); // bf16 x
    u16* BH   = (u16*)alloc(hbytes);   // h1 -> h2 -> hid3
    u16* BA   = (u16*)alloc(hbytes);   // agg1 -> agg2
    u16* WT1  = (u16*)alloc((size_t)HIDC * F_IN * sizeof(u16));
    u16* WT2  = (u16*)alloc((size_t)HIDC * HIDC * sizeof(u16));
    u16* WQT  = (u16*)alloc((size_t)HIDC * HIDC * sizeof(u16));
    // pairs sharing one memset are single allocations (alloc rounds to 256B!)
    float* asrc = (float*)alloc((size_t)N * 4 * 4 * 2);      // asrc | adst
    float* adst = asrc + (size_t)N * 4;
    int* rowptr  = (int*)alloc((size_t)(N + 1) * 4);
    int* csr_src = (int*)alloc((size_t)Etot * 4);
    int* cur     = (int*)alloc((size_t)N * 4 * 2);           // deg | fill cursor
    int* cur2    = cur + N;
    int* part    = (int*)alloc((size_t)N * 4);
    int* bsum    = (int*)alloc((size_t)nb * 4);
    float* bnsum = (float*)alloc(HIDC * 4 * 2);              // bnsum | bnsq
    float* bnsq  = bnsum + HIDC;
    float* sc1   = (float*)alloc(HIDC * 4);
    float* bi1   = (float*)alloc(HIDC * 4);
    float* sc2   = (float*)alloc(HIDC * 4);
    float* bi2   = (float*)alloc(HIDC * 4);
    float* gsum  = (float*)alloc((NG * HIDC + NG) * 4);      // gsum | gcnt
    float* gcnt  = gsum + NG * HIDC;
    float* gproj = (float*)alloc(NG * HIDC * 4);

    dim3 gemmGrid(2, (N + 127) / 128);   // block = 128 rows x 128 cols
    int edgeBlocks = (Etot + 255) / 256;
    int nodeBlocksW = (N + 3) / 4;

    // ===================== CSR build (once) ==============================
    hipMemsetAsync(cur, 0, (size_t)N * 4 * 2, stream);        // cur + cur2
    deg_kernel<<<edgeBlocks, 256, 0, stream>>>(ei, E, N, cur);
    scan_phase1<<<nb, 256, 0, stream>>>(cur, part, bsum, N);
    scan_phase2<<<1, 256, 0, stream>>>(bsum, nb);
    scan_phase3<<<nb, 256, 0, stream>>>(part, bsum, rowptr, N);
    fill_kernel<<<edgeBlocks, 256, 0, stream>>>(ei, E, N, rowptr, cur2, csr_src);

    // ===================== prep: bf16 conversions ========================
    f2b2_kernel<<<(N * F_IN / 2 + 255) / 256, 256, 0, stream>>>(x, (u32*)BX, N * F_IN / 2);
    wt_kernel<<<(F_IN * HIDC + 255) / 256, 256, 0, stream>>>(W1, WT1, F_IN, HIDC);
    wt_kernel<<<(HIDC * HIDC + 255) / 256, 256, 0, stream>>>(W2, WT2, HIDC, HIDC);
    wt_kernel<<<(HIDC * HIDC + 255) / 256, 256, 0, stream>>>(Wq1, WQT, HIDC, HIDC);

    // ===================== Layer 1: GEMM(+alpha4) -> gather -> BN stats ==
    gemm_mfma_kernel<F_IN, 0><<<gemmGrid, 256, 0, stream>>>(
        BX, WT1, BH, N, nullptr, nullptr, as1, ad1, asrc, adst, nullptr, nullptr, nullptr);
    gat_gather_kernel<4><<<nodeBlocksW, 256, 0, stream>>>(rowptr, csr_src, asrc, adst, BH, BA, N);
    hipMemsetAsync(bnsum, 0, HIDC * 4 * 2, stream);           // bnsum + bnsq
    bn_stats_kernel<<<(N + 127) / 128, 256, 0, stream>>>(BA, N, bnsum, bnsq);
    bn_coef_kernel<<<1, HIDC, 0, stream>>>(bnsum, bnsq, g1, be1, sc1, bi1, N);

    // ===================== Layer 2: GEMM(BN-A, +alpha1) -> gather -> BN ==
    hipMemsetAsync(asrc, 0, (size_t)N * 4 * 4 * 2, stream);   // asrc + adst
    gemm_mfma_kernel<HIDC, 1><<<gemmGrid, 256, 0, stream>>>(
        BA, WT2, BH, N, sc1, bi1, as2, ad2, asrc, adst, nullptr, nullptr, nullptr);
    gat_gather_kernel<1><<<nodeBlocksW, 256, 0, stream>>>(rowptr, csr_src, asrc, adst, BH, BA, N);
    hipMemsetAsync(bnsum, 0, HIDC * 4 * 2, stream);
    bn_stats_kernel<<<(N + 127) / 128, 256, 0, stream>>>(BA, N, bnsum, bnsq);
    bn_coef_kernel<<<1, HIDC, 0, stream>>>(bnsum, bnsq, g2, be2, sc2, bi2, N);

    // ===================== Pool (BN inline) + projection =================
    hipMemsetAsync(gsum, 0, (NG * HIDC + NG) * 4, stream);    // gsum + gcnt
    pool_bn_kernel<<<(N + 127) / 128, 256, 0, stream>>>(BA, bat, N, sc2, bi2, gsum, gcnt);
    gmean_gproj_kernel<<<NG, HIDC, 0, stream>>>(gsum, gcnt, Wq1, gproj);

    // ===================== Head: GEMM(BN-A, fused epilogue) -> q =========
    gemm_mfma_kernel<HIDC, 2><<<gemmGrid, 256, 0, stream>>>(
        BA, WQT, BH, N, sc2, bi2, nullptr, nullptr, nullptr, nullptr, gproj, bat, bq1);
    q_kernel<<<nodeBlocksW, 256, 0, stream>>>(BH, Wq2, bq2, bat, out, N);
}